// Round 1
// baseline (22619.345 us; speedup 1.0000x reference)
//
#include <hip/hip_runtime.h>
#include <cstdint>
#include <cstddef>

#define NN 32768
#define NE 524288
#define H  128
#define H3 384
#define RB 64
#define EB 16

#define INV_SQRT_3 0.5773502691896258f
#define INV_SQRT_H 0.08838834764831845f
#define INV_SQRT_2 0.7071067811865476f

__device__ __forceinline__ float scaled_silu(float v) {
    return v * (1.0f / 0.6f) / (1.0f + __expf(-v));
}

// ---------------- LayerNorm: t = LN(x) --------------------------------------
// one wave per row; 4 rows per 256-thread block
__global__ __launch_bounds__(256) void ln_kernel(const float* __restrict__ x,
        const float* __restrict__ g, const float* __restrict__ b,
        float* __restrict__ t) {
    int row  = blockIdx.x * 4 + (threadIdx.x >> 6);
    int lane = threadIdx.x & 63;
    const float* xr = x + (size_t)row * H;
    float v0 = xr[lane], v1 = xr[lane + 64];
    float s = v0 + v1;
#pragma unroll
    for (int off = 32; off; off >>= 1) s += __shfl_xor(s, off, 64);
    float mu = s * (1.0f / 128.0f);
    float d0 = v0 - mu, d1 = v1 - mu;
    float q = d0 * d0 + d1 * d1;
#pragma unroll
    for (int off = 32; off; off >>= 1) q += __shfl_xor(q, off, 64);
    float rs = rsqrtf(q * (1.0f / 128.0f) + 1e-5f);
    float* tr = t + (size_t)row * H;
    tr[lane]      = d0 * rs * g[lane]      + b[lane];
    tr[lane + 64] = d1 * rs * g[lane + 64] + b[lane + 64];
}

// ---------------- G1: h1 = scaled_silu(t @ W1 + b1)  [N,128]x[128,128] ------
__global__ __launch_bounds__(256) void g1_kernel(const float* __restrict__ t,
        const float* __restrict__ W1, const float* __restrict__ b1,
        float* __restrict__ h1) {
    __shared__ float WL[128 * 128];  // 64KB
    __shared__ float AL[32 * 128];   // 16KB
    int tid = threadIdx.x;
    int r0 = blockIdx.x * 32;
#pragma unroll
    for (int q = 0; q < 16; ++q)
        ((float4*)WL)[tid + 256 * q] = ((const float4*)W1)[tid + 256 * q];
#pragma unroll
    for (int q = 0; q < 4; ++q)
        ((float4*)AL)[tid + 256 * q] = ((const float4*)(t + (size_t)r0 * H))[tid + 256 * q];
    __syncthreads();
    int c2 = tid & 63, rg = tid >> 6;
    float acc0[8], acc1[8];
#pragma unroll
    for (int r = 0; r < 8; ++r) { acc0[r] = 0.f; acc1[r] = 0.f; }
    const float4* AL4 = (const float4*)AL;
#pragma unroll 4
    for (int k4 = 0; k4 < 32; ++k4) {
        float w0[4], w1[4];
#pragma unroll
        for (int i = 0; i < 4; ++i) {
            w0[i] = WL[(k4 * 4 + i) * 128 + c2];
            w1[i] = WL[(k4 * 4 + i) * 128 + c2 + 64];
        }
#pragma unroll
        for (int r = 0; r < 8; ++r) {
            float4 a = AL4[(rg * 8 + r) * 32 + k4];
            acc0[r] += a.x * w0[0] + a.y * w0[1] + a.z * w0[2] + a.w * w0[3];
            acc1[r] += a.x * w1[0] + a.y * w1[1] + a.z * w1[2] + a.w * w1[3];
        }
    }
    float bb0 = b1[c2], bb1 = b1[c2 + 64];
#pragma unroll
    for (int r = 0; r < 8; ++r) {
        int row = r0 + rg * 8 + r;
        h1[(size_t)row * H + c2]      = scaled_silu(acc0[r] + bb0);
        h1[(size_t)row * H + c2 + 64] = scaled_silu(acc1[r] + bb1);
    }
}

// ---------------- G2: xh = h1 @ W2 + b2  [N,128]x[128,384] ------------------
__global__ __launch_bounds__(256) void g2_kernel(const float* __restrict__ h1,
        const float* __restrict__ W2, const float* __restrict__ b2,
        float* __restrict__ xh) {
    __shared__ float WL[128 * 128];  // one 128-col slice of W2
    __shared__ float AL[32 * 128];
    int tid = threadIdx.x;
    int r0 = blockIdx.x * 32;
#pragma unroll
    for (int q = 0; q < 4; ++q)
        ((float4*)AL)[tid + 256 * q] = ((const float4*)(h1 + (size_t)r0 * H))[tid + 256 * q];
    int c2 = tid & 63, rg = tid >> 6;
    const float4* AL4 = (const float4*)AL;
    for (int s = 0; s < 3; ++s) {
        __syncthreads();
#pragma unroll
        for (int q = 0; q < 16; ++q) {
            int i4 = tid + 256 * q;
            int kk = i4 >> 5, c4 = i4 & 31;
            ((float4*)WL)[i4] = ((const float4*)(W2 + (size_t)kk * H3 + s * H))[c4];
        }
        __syncthreads();
        float acc0[8], acc1[8];
#pragma unroll
        for (int r = 0; r < 8; ++r) { acc0[r] = 0.f; acc1[r] = 0.f; }
#pragma unroll 4
        for (int k4 = 0; k4 < 32; ++k4) {
            float w0[4], w1[4];
#pragma unroll
            for (int i = 0; i < 4; ++i) {
                w0[i] = WL[(k4 * 4 + i) * 128 + c2];
                w1[i] = WL[(k4 * 4 + i) * 128 + c2 + 64];
            }
#pragma unroll
            for (int r = 0; r < 8; ++r) {
                float4 a = AL4[(rg * 8 + r) * 32 + k4];
                acc0[r] += a.x * w0[0] + a.y * w0[1] + a.z * w0[2] + a.w * w0[3];
                acc1[r] += a.x * w1[0] + a.y * w1[1] + a.z * w1[2] + a.w * w1[3];
            }
        }
        float bb0 = b2[s * H + c2], bb1 = b2[s * H + c2 + 64];
#pragma unroll
        for (int r = 0; r < 8; ++r) {
            int row = r0 + rg * 8 + r;
            xh[(size_t)row * H3 + s * H + c2]      = acc0[r] + bb0;
            xh[(size_t)row * H3 + s * H + c2 + 64] = acc1[r] + bb1;
        }
    }
}

// ---------------- Edge kernel: fused rbfh GEMM + message + scatter ----------
// block = 384 threads (thread j = column of 3H). Wr column held in 64 VGPRs.
__global__ __launch_bounds__(384) void edge_kernel(
        const int* __restrict__ eidx, const float* __restrict__ eembed,
        const float* __restrict__ evec, const float* __restrict__ Wr,
        const float* __restrict__ br, const float* __restrict__ xh,
        const float* __restrict__ vec, float* __restrict__ dx_acc,
        float* __restrict__ dvec_acc) {
    __shared__ float eeL[EB * RB];   // 4KB
    __shared__ float mst[EB * H3];   // 24KB
    __shared__ int   sSrc[EB];
    __shared__ int   sDst[EB];
    __shared__ float sEv[EB][3];
    int j = threadIdx.x;  // 0..383
    float4 wreg[16];
#pragma unroll
    for (int r4 = 0; r4 < 16; ++r4) {
        wreg[r4].x = Wr[(r4 * 4 + 0) * H3 + j];
        wreg[r4].y = Wr[(r4 * 4 + 1) * H3 + j];
        wreg[r4].z = Wr[(r4 * 4 + 2) * H3 + j];
        wreg[r4].w = Wr[(r4 * 4 + 3) * H3 + j];
    }
    float brj = brj = br[j];
    int c = j >> 7;
    int hh = j & 127;
    const int nchunk = NE / EB;
    for (int ch = blockIdx.x; ch < nchunk; ch += gridDim.x) {
        int e0 = ch * EB;
        for (int i = j; i < EB * RB; i += 384) eeL[i] = eembed[(size_t)e0 * RB + i];
        if (j < EB) { sSrc[j] = eidx[e0 + j]; sDst[j] = eidx[NE + e0 + j]; }
        if (j >= 64 && j < 64 + EB * 3) {
            int i = j - 64;
            sEv[i / 3][i % 3] = evec[(size_t)e0 * 3 + i];
        }
        __syncthreads();
        // rbfh = ee @ Wr + br, one column per thread, 16 edges in registers
        float acc[EB];
#pragma unroll
        for (int e = 0; e < EB; ++e) acc[e] = brj;
#pragma unroll
        for (int r4 = 0; r4 < 16; ++r4) {
            float4 w = wreg[r4];
#pragma unroll
            for (int e = 0; e < EB; ++e) {
                float4 a = *(const float4*)&eeL[e * RB + r4 * 4];
                acc[e] += a.x * w.x + a.y * w.y + a.z * w.z + a.w * w.w;
            }
        }
        // m = xh[src] * rbfh ; dx scatter (first H columns)
#pragma unroll
        for (int e = 0; e < EB; ++e) {
            float m = xh[(size_t)sSrc[e] * H3 + j] * acc[e];
            mst[e * H3 + j] = m;
            if (j < H) atomicAdd(&dx_acc[(size_t)sDst[e] * H + j], m);
        }
        __syncthreads();
        // vec messages: vmsg = (vec[src]*xh2 + xh3*edge_vec)*INV_SQRT_H
#pragma unroll
        for (int e = 0; e < EB; ++e) {
            float m2 = mst[e * H3 + H + hh] * INV_SQRT_3;
            float m3 = mst[e * H3 + 2 * H + hh];
            float vs = vec[(size_t)sSrc[e] * H3 + j];  // j == c*128+hh
            float vmsg = (vs * m2 + m3 * sEv[e][c]) * INV_SQRT_H;
            atomicAdd(&dvec_acc[(size_t)sDst[e] * H3 + j], vmsg);
        }
        __syncthreads();
    }
}

// ---------------- D1: vec_mid/x_mid + vproj (Wv), vec1/vec_dot/vec2_norm ----
// 8 nodes per block
__global__ __launch_bounds__(256) void d1_kernel(
        const float* __restrict__ x, const float* __restrict__ vec,
        const float* __restrict__ Wv,
        float* __restrict__ B1 /* in dvec, out vec_mid */,
        float* __restrict__ B2 /* in dx, out x_mid */,
        float* __restrict__ B0 /* out vec1 */,
        float* __restrict__ B3 /* out vec_dot */,
        float* __restrict__ B4 /* out vec2_norm */) {
    __shared__ float vmL[8 * H3];    // 12KB
    __shared__ float WL[128 * 128];  // 64KB
    int tid = threadIdx.x;
    int n0 = blockIdx.x * 8;
    for (int i = tid; i < 8 * H3; i += 256) {
        float vm = vec[(size_t)n0 * H3 + i] + B1[(size_t)n0 * H3 + i];
        B1[(size_t)n0 * H3 + i] = vm;
        vmL[i] = vm;
    }
    for (int i = tid; i < 8 * H; i += 256) {
        float xm = (x[(size_t)n0 * H + i] + B2[(size_t)n0 * H + i]) * INV_SQRT_2;
        B2[(size_t)n0 * H + i] = xm;
    }
    int k = tid & 127, ng = tid >> 7;
    const float4* vmL4 = (const float4*)vmL;
    float a1[4][3], a2[4][3];
    // ---- slice 0 (vec1) ----
    __syncthreads();
#pragma unroll
    for (int q = 0; q < 16; ++q) {
        int i4 = tid + 256 * q;
        int h = i4 >> 5, c4 = i4 & 31;
        ((float4*)WL)[i4] = ((const float4*)(Wv + (size_t)h * 256))[c4];
    }
    __syncthreads();
#pragma unroll
    for (int n = 0; n < 4; ++n)
#pragma unroll
        for (int cc = 0; cc < 3; ++cc) a1[n][cc] = 0.f;
#pragma unroll 4
    for (int h4 = 0; h4 < 32; ++h4) {
        float w[4];
#pragma unroll
        for (int i = 0; i < 4; ++i) w[i] = WL[(h4 * 4 + i) * 128 + k];
#pragma unroll
        for (int n = 0; n < 4; ++n)
#pragma unroll
            for (int cc = 0; cc < 3; ++cc) {
                float4 a = vmL4[((ng * 4 + n) * 3 + cc) * 32 + h4];
                a1[n][cc] += a.x * w[0] + a.y * w[1] + a.z * w[2] + a.w * w[3];
            }
    }
#pragma unroll
    for (int n = 0; n < 4; ++n)
#pragma unroll
        for (int cc = 0; cc < 3; ++cc)
            B0[(size_t)(n0 + ng * 4 + n) * H3 + cc * H + k] = a1[n][cc];
    // ---- slice 1 (vec2) ----
    __syncthreads();
#pragma unroll
    for (int q = 0; q < 16; ++q) {
        int i4 = tid + 256 * q;
        int h = i4 >> 5, c4 = i4 & 31;
        ((float4*)WL)[i4] = ((const float4*)(Wv + (size_t)h * 256 + 128))[c4];
    }
    __syncthreads();
#pragma unroll
    for (int n = 0; n < 4; ++n)
#pragma unroll
        for (int cc = 0; cc < 3; ++cc) a2[n][cc] = 0.f;
#pragma unroll 4
    for (int h4 = 0; h4 < 32; ++h4) {
        float w[4];
#pragma unroll
        for (int i = 0; i < 4; ++i) w[i] = WL[(h4 * 4 + i) * 128 + k];
#pragma unroll
        for (int n = 0; n < 4; ++n)
#pragma unroll
            for (int cc = 0; cc < 3; ++cc) {
                float4 a = vmL4[((ng * 4 + n) * 3 + cc) * 32 + h4];
                a2[n][cc] += a.x * w[0] + a.y * w[1] + a.z * w[2] + a.w * w[3];
            }
    }
#pragma unroll
    for (int n = 0; n < 4; ++n) {
        int gn = n0 + ng * 4 + n;
        float dot = (a1[n][0] * a2[n][0] + a1[n][1] * a2[n][1] + a1[n][2] * a2[n][2]) * INV_SQRT_H;
        float nrm = sqrtf(a2[n][0] * a2[n][0] + a2[n][1] * a2[n][1] + a2[n][2] * a2[n][2] + 1e-8f);
        B3[(size_t)gn * H + k] = dot;
        B4[(size_t)gn * H + k] = nrm;
    }
}

// ---------------- D2a: u = scaled_silu([x_mid, vnorm] @ Wu1 + bu1) ----------
// 16 nodes per block; u overwrites vnorm buffer (B4)
__global__ __launch_bounds__(256) void d2a_kernel(
        const float* __restrict__ Wu1, const float* __restrict__ bu1,
        const float* __restrict__ B2 /* x_mid */,
        float* __restrict__ B4 /* in vnorm, out u */) {
    __shared__ float catL[16 * 256];  // 16KB
    __shared__ float WL[128 * 128];   // 64KB
    int tid = threadIdx.x;
    int n0 = blockIdx.x * 16;
    for (int i = tid; i < 16 * 256; i += 256) {
        int n = i >> 8, kk = i & 255;
        catL[i] = (kk < 128) ? B2[(size_t)(n0 + n) * H + kk]
                             : B4[(size_t)(n0 + n) * H + kk - 128];
    }
    int c = tid & 127, ng = tid >> 7;
    float acc[8];
#pragma unroll
    for (int n = 0; n < 8; ++n) acc[n] = 0.f;
    const float4* catL4 = (const float4*)catL;
    for (int half = 0; half < 2; ++half) {
        __syncthreads();
#pragma unroll
        for (int q = 0; q < 16; ++q)
            ((float4*)WL)[tid + 256 * q] =
                ((const float4*)(Wu1 + (size_t)half * 128 * 128))[tid + 256 * q];
        __syncthreads();
#pragma unroll 4
        for (int k4 = 0; k4 < 32; ++k4) {
            float w[4];
#pragma unroll
            for (int i = 0; i < 4; ++i) w[i] = WL[(k4 * 4 + i) * 128 + c];
#pragma unroll
            for (int n = 0; n < 8; ++n) {
                float4 a = catL4[(ng * 8 + n) * 64 + half * 32 + k4];
                acc[n] += a.x * w[0] + a.y * w[1] + a.z * w[2] + a.w * w[3];
            }
        }
    }
    float bb = bu1[c];
#pragma unroll
    for (int n = 0; n < 8; ++n)
        B4[(size_t)(n0 + ng * 8 + n) * H + c] = scaled_silu(acc[n] + bb);
}

// ---------------- D2b: hh = u @ Wu2 + bu2, final outputs --------------------
// 16 nodes per block; 3 col-slices of Wu2
__global__ __launch_bounds__(256) void d2b_kernel(
        const float* __restrict__ Wu2, const float* __restrict__ bu2,
        const float* __restrict__ B4 /* u */, const float* __restrict__ B3 /* vec_dot */,
        const float* __restrict__ B2 /* x_mid */, const float* __restrict__ B1 /* vec_mid */,
        const float* __restrict__ B0 /* vec1 */, float* __restrict__ out) {
    __shared__ float uL[16 * 128];     // 8KB
    __shared__ float WL[128 * 128];    // 64KB
    __shared__ float stash[16 * 128];  // 8KB (xv1)
    int tid = threadIdx.x;
    int n0 = blockIdx.x * 16;
#pragma unroll
    for (int q = 0; q < 2; ++q)
        ((float4*)uL)[tid + 256 * q] = ((const float4*)(B4 + (size_t)n0 * H))[tid + 256 * q];
    int c = tid & 127, ng = tid >> 7;
    const float4* uL4 = (const float4*)uL;
    float* out_vec = out;
    float* out_x = out + (size_t)NN * H3;
    for (int s = 0; s < 3; ++s) {
        __syncthreads();
#pragma unroll
        for (int q = 0; q < 16; ++q) {
            int i4 = tid + 256 * q;
            int kk = i4 >> 5, c4 = i4 & 31;
            ((float4*)WL)[i4] = ((const float4*)(Wu2 + (size_t)kk * H3 + s * H))[c4];
        }
        __syncthreads();
        float acc[8];
#pragma unroll
        for (int n = 0; n < 8; ++n) acc[n] = 0.f;
#pragma unroll 4
        for (int k4 = 0; k4 < 32; ++k4) {
            float w[4];
#pragma unroll
            for (int i = 0; i < 4; ++i) w[i] = WL[(k4 * 4 + i) * 128 + c];
#pragma unroll
            for (int n = 0; n < 8; ++n) {
                float4 a = uL4[(ng * 8 + n) * 32 + k4];
                acc[n] += a.x * w[0] + a.y * w[1] + a.z * w[2] + a.w * w[3];
            }
        }
        float bb = bu2[s * H + c];
        if (s == 0) {
#pragma unroll
            for (int n = 0; n < 8; ++n)
                stash[(ng * 8 + n) * 128 + c] = acc[n] + bb;
        } else if (s == 1) {
#pragma unroll
            for (int n = 0; n < 8; ++n) {
                int gn = n0 + ng * 8 + n;
                float xv2 = acc[n] + bb;
                float dx2 = (stash[(ng * 8 + n) * 128 + c] +
                             xv2 * B3[(size_t)gn * H + c]) * INV_SQRT_2;
                out_x[(size_t)gn * H + c] = B2[(size_t)gn * H + c] + dx2;
            }
        } else {
#pragma unroll
            for (int n = 0; n < 8; ++n) {
                int gn = n0 + ng * 8 + n;
                float xv3 = acc[n] + bb;
#pragma unroll
                for (int c3 = 0; c3 < 3; ++c3) {
                    size_t idx = (size_t)gn * H3 + c3 * H + c;
                    out_vec[idx] = B1[idx] + xv3 * B0[idx];
                }
            }
        }
    }
}

extern "C" void kernel_launch(void* const* d_in, const int* in_sizes, int n_in,
                              void* d_out, int out_size, void* d_ws, size_t ws_size,
                              hipStream_t stream) {
    const float* x    = (const float*)d_in[0];
    const float* vec  = (const float*)d_in[1];
    const int*   eidx = (const int*)d_in[2];
    const float* eemb = (const float*)d_in[3];
    const float* evec = (const float*)d_in[4];
    const float* lng  = (const float*)d_in[5];
    const float* lnb  = (const float*)d_in[6];
    const float* W1   = (const float*)d_in[7];
    const float* b1   = (const float*)d_in[8];
    const float* W2   = (const float*)d_in[9];
    const float* b2   = (const float*)d_in[10];
    const float* Wr   = (const float*)d_in[11];
    const float* br   = (const float*)d_in[12];
    const float* Wv   = (const float*)d_in[13];
    const float* Wu1  = (const float*)d_in[14];
    const float* bu1  = (const float*)d_in[15];
    const float* Wu2  = (const float*)d_in[16];
    const float* bu2  = (const float*)d_in[17];

    // workspace layout (fp32):
    // B0: N*384  xh -> vec1
    // B1: N*384  dvec_acc -> vec_mid
    // B2: N*128  t(LN) -> dx_acc -> x_mid
    // B3: N*128  h1 -> vec_dot
    // B4: N*128  vec2_norm -> u
    float* B0 = (float*)d_ws;
    float* B1 = B0 + (size_t)NN * H3;
    float* B2 = B1 + (size_t)NN * H3;
    float* B3 = B2 + (size_t)NN * H;
    float* B4 = B3 + (size_t)NN * H;
    float* out = (float*)d_out;

    ln_kernel<<<NN / 4, 256, 0, stream>>>(x, lng, lnb, B2);
    g1_kernel<<<NN / 32, 256, 0, stream>>>(B2, W1, b1, B3);
    g2_kernel<<<NN / 32, 256, 0, stream>>>(B3, W2, b2, B0);
    hipMemsetAsync(B1, 0, (size_t)NN * H3 * sizeof(float), stream);
    hipMemsetAsync(B2, 0, (size_t)NN * H * sizeof(float), stream);
    edge_kernel<<<4096, 384, 0, stream>>>(eidx, eemb, evec, Wr, br, B0, vec, B2, B1);
    d1_kernel<<<NN / 8, 256, 0, stream>>>(x, vec, Wv, B1, B2, B0, B3, B4);
    d2a_kernel<<<NN / 16, 256, 0, stream>>>(Wu1, bu1, B2, B4);
    d2b_kernel<<<NN / 16, 256, 0, stream>>>(Wu2, bu2, B4, B3, B2, B1, B0, out);
}

// Round 2
// 2638.308 us; speedup vs baseline: 8.5734x; 8.5734x over previous
//
#include <hip/hip_runtime.h>
#include <cstdint>
#include <cstddef>

#define NN 32768
#define NE 524288
#define H  128
#define H3 384
#define RB 64
#define EB 16
#define NPB 8   // dst nodes per block in edge_csr

#define INV_SQRT_3 0.5773502691896258f
#define INV_SQRT_H 0.08838834764831845f
#define INV_SQRT_2 0.7071067811865476f

__device__ __forceinline__ float scaled_silu(float v) {
    return v * (1.0f / 0.6f) / (1.0f + __expf(-v));
}

// ---------------- LayerNorm: t = LN(x) --------------------------------------
__global__ __launch_bounds__(256) void ln_kernel(const float* __restrict__ x,
        const float* __restrict__ g, const float* __restrict__ b,
        float* __restrict__ t) {
    int row  = blockIdx.x * 4 + (threadIdx.x >> 6);
    int lane = threadIdx.x & 63;
    const float* xr = x + (size_t)row * H;
    float v0 = xr[lane], v1 = xr[lane + 64];
    float s = v0 + v1;
#pragma unroll
    for (int off = 32; off; off >>= 1) s += __shfl_xor(s, off, 64);
    float mu = s * (1.0f / 128.0f);
    float d0 = v0 - mu, d1 = v1 - mu;
    float q = d0 * d0 + d1 * d1;
#pragma unroll
    for (int off = 32; off; off >>= 1) q += __shfl_xor(q, off, 64);
    float rs = rsqrtf(q * (1.0f / 128.0f) + 1e-5f);
    float* tr = t + (size_t)row * H;
    tr[lane]      = d0 * rs * g[lane]      + b[lane];
    tr[lane + 64] = d1 * rs * g[lane + 64] + b[lane + 64];
}

// ---------------- G1: h1 = scaled_silu(t @ W1 + b1) -------------------------
__global__ __launch_bounds__(256) void g1_kernel(const float* __restrict__ t,
        const float* __restrict__ W1, const float* __restrict__ b1,
        float* __restrict__ h1) {
    __shared__ float WL[128 * 128];
    __shared__ float AL[32 * 128];
    int tid = threadIdx.x;
    int r0 = blockIdx.x * 32;
#pragma unroll
    for (int q = 0; q < 16; ++q)
        ((float4*)WL)[tid + 256 * q] = ((const float4*)W1)[tid + 256 * q];
#pragma unroll
    for (int q = 0; q < 4; ++q)
        ((float4*)AL)[tid + 256 * q] = ((const float4*)(t + (size_t)r0 * H))[tid + 256 * q];
    __syncthreads();
    int c2 = tid & 63, rg = tid >> 6;
    float acc0[8], acc1[8];
#pragma unroll
    for (int r = 0; r < 8; ++r) { acc0[r] = 0.f; acc1[r] = 0.f; }
    const float4* AL4 = (const float4*)AL;
#pragma unroll 4
    for (int k4 = 0; k4 < 32; ++k4) {
        float w0[4], w1[4];
#pragma unroll
        for (int i = 0; i < 4; ++i) {
            w0[i] = WL[(k4 * 4 + i) * 128 + c2];
            w1[i] = WL[(k4 * 4 + i) * 128 + c2 + 64];
        }
#pragma unroll
        for (int r = 0; r < 8; ++r) {
            float4 a = AL4[(rg * 8 + r) * 32 + k4];
            acc0[r] += a.x * w0[0] + a.y * w0[1] + a.z * w0[2] + a.w * w0[3];
            acc1[r] += a.x * w1[0] + a.y * w1[1] + a.z * w1[2] + a.w * w1[3];
        }
    }
    float bb0 = b1[c2], bb1 = b1[c2 + 64];
#pragma unroll
    for (int r = 0; r < 8; ++r) {
        int row = r0 + rg * 8 + r;
        h1[(size_t)row * H + c2]      = scaled_silu(acc0[r] + bb0);
        h1[(size_t)row * H + c2 + 64] = scaled_silu(acc1[r] + bb1);
    }
}

// ---------------- G2: xh = h1 @ W2 + b2 -------------------------------------
__global__ __launch_bounds__(256) void g2_kernel(const float* __restrict__ h1,
        const float* __restrict__ W2, const float* __restrict__ b2,
        float* __restrict__ xh) {
    __shared__ float WL[128 * 128];
    __shared__ float AL[32 * 128];
    int tid = threadIdx.x;
    int r0 = blockIdx.x * 32;
#pragma unroll
    for (int q = 0; q < 4; ++q)
        ((float4*)AL)[tid + 256 * q] = ((const float4*)(h1 + (size_t)r0 * H))[tid + 256 * q];
    int c2 = tid & 63, rg = tid >> 6;
    const float4* AL4 = (const float4*)AL;
    for (int s = 0; s < 3; ++s) {
        __syncthreads();
#pragma unroll
        for (int q = 0; q < 16; ++q) {
            int i4 = tid + 256 * q;
            int kk = i4 >> 5, c4 = i4 & 31;
            ((float4*)WL)[i4] = ((const float4*)(W2 + (size_t)kk * H3 + s * H))[c4];
        }
        __syncthreads();
        float acc0[8], acc1[8];
#pragma unroll
        for (int r = 0; r < 8; ++r) { acc0[r] = 0.f; acc1[r] = 0.f; }
#pragma unroll 4
        for (int k4 = 0; k4 < 32; ++k4) {
            float w0[4], w1[4];
#pragma unroll
            for (int i = 0; i < 4; ++i) {
                w0[i] = WL[(k4 * 4 + i) * 128 + c2];
                w1[i] = WL[(k4 * 4 + i) * 128 + c2 + 64];
            }
#pragma unroll
            for (int r = 0; r < 8; ++r) {
                float4 a = AL4[(rg * 8 + r) * 32 + k4];
                acc0[r] += a.x * w0[0] + a.y * w0[1] + a.z * w0[2] + a.w * w0[3];
                acc1[r] += a.x * w1[0] + a.y * w1[1] + a.z * w1[2] + a.w * w1[3];
            }
        }
        float bb0 = b2[s * H + c2], bb1 = b2[s * H + c2 + 64];
#pragma unroll
        for (int r = 0; r < 8; ++r) {
            int row = r0 + rg * 8 + r;
            xh[(size_t)row * H3 + s * H + c2]      = acc0[r] + bb0;
            xh[(size_t)row * H3 + s * H + c2 + 64] = acc1[r] + bb1;
        }
    }
}

// ---------------- Sort pass 1: histogram of dst -----------------------------
__global__ __launch_bounds__(256) void hist_kernel(const int* __restrict__ eidx,
        int* __restrict__ hist) {
    int e = blockIdx.x * 256 + threadIdx.x;
    atomicAdd(&hist[eidx[NE + e]], 1);
}

// ---------------- Sort pass 2: exclusive scan of 32768 counts ---------------
// hist aliases row_ptr (in-place safe: each thread reads its range before any write)
__global__ __launch_bounds__(1024) void scan_kernel(const int* __restrict__ hist,
        int* __restrict__ row_ptr, int* __restrict__ cursor) {
    __shared__ int sc[1024];
    int t = threadIdx.x;
    int base = t * 32;
    int v[32];
    int s = 0;
#pragma unroll
    for (int i = 0; i < 32; ++i) {
        int tmp = hist[base + i];
        v[i] = s;
        s += tmp;
    }
    sc[t] = s;
    __syncthreads();
    for (int off = 1; off < 1024; off <<= 1) {
        int a = sc[t];
        int b = (t >= off) ? sc[t - off] : 0;
        __syncthreads();
        sc[t] = a + b;
        __syncthreads();
    }
    int excl = sc[t] - s;
#pragma unroll
    for (int i = 0; i < 32; ++i) {
        int val = excl + v[i];
        row_ptr[base + i] = val;
        cursor[base + i] = val;
    }
    if (t == 0) row_ptr[32768] = NE;
}

// ---------------- Sort pass 3: scatter edges into dst-sorted order ----------
__global__ __launch_bounds__(256) void scatter_kernel(const int* __restrict__ eidx,
        const float* __restrict__ evec, int* __restrict__ cursor,
        int* __restrict__ perm, int* __restrict__ srcs_s, int* __restrict__ dsts_s,
        float* __restrict__ ev_s) {
    int e = blockIdx.x * 256 + threadIdx.x;
    int d = eidx[NE + e];
    int pos = atomicAdd(&cursor[d], 1);
    perm[pos]   = e;
    srcs_s[pos] = eidx[e];
    dsts_s[pos] = d;
    ev_s[pos * 3 + 0] = evec[e * 3 + 0];
    ev_s[pos * 3 + 1] = evec[e * 3 + 1];
    ev_s[pos * 3 + 2] = evec[e * 3 + 2];
}

// ---------------- Edge kernel (CSR): fused rbf GEMM + message + LDS reduce --
// block = 384 threads (thread j = column of 3H), owns NPB consecutive dst nodes.
__global__ __launch_bounds__(384) void edge_csr_kernel(
        const int* __restrict__ row_ptr, const int* __restrict__ perm,
        const int* __restrict__ srcs_s, const int* __restrict__ dsts_s,
        const float* __restrict__ ev_s, const float* __restrict__ eembed,
        const float* __restrict__ Wr, const float* __restrict__ br,
        const float* __restrict__ xh, const float* __restrict__ vec,
        float* __restrict__ dx_out, float* __restrict__ dvec_out) {
    __shared__ float accdx[NPB * H];    // 4KB
    __shared__ float accdv[NPB * H3];   // 12KB
    __shared__ float eeL[EB * RB];      // 4KB
    __shared__ float mst[EB * H3];      // 24KB
    __shared__ int   sSrc[EB];
    __shared__ int   sLd[EB];
    __shared__ float sEv[EB][3];
    int j = threadIdx.x;  // 0..383
    // Wr column j in registers (64 VGPRs)
    float4 wreg[16];
#pragma unroll
    for (int r4 = 0; r4 < 16; ++r4) {
        wreg[r4].x = Wr[(r4 * 4 + 0) * H3 + j];
        wreg[r4].y = Wr[(r4 * 4 + 1) * H3 + j];
        wreg[r4].z = Wr[(r4 * 4 + 2) * H3 + j];
        wreg[r4].w = Wr[(r4 * 4 + 3) * H3 + j];
    }
    float brj = br[j];
    int n0 = blockIdx.x * NPB;
    for (int i = j; i < NPB * H;  i += 384) accdx[i] = 0.f;
    for (int i = j; i < NPB * H3; i += 384) accdv[i] = 0.f;
    int ib = row_ptr[n0], ie = row_ptr[n0 + NPB];
    int c = j >> 7, hh = j & 127;
    __syncthreads();
    for (int base = ib; base < ie; base += EB) {
        int cnt = min(EB, ie - base);
        if (j < EB) {
            int i = base + ((j < cnt) ? j : 0);
            sSrc[j] = srcs_s[i];
            sLd[j]  = (j < cnt) ? (dsts_s[i] - n0) : -1;
            sEv[j][0] = ev_s[(size_t)i * 3 + 0];
            sEv[j][1] = ev_s[(size_t)i * 3 + 1];
            sEv[j][2] = ev_s[(size_t)i * 3 + 2];
        }
        if (j < 256) {
            int r = j >> 4, c4 = j & 15;
            int i = base + ((r < cnt) ? r : 0);
            int p = perm[i];
            ((float4*)eeL)[j] = ((const float4*)(eembed + (size_t)p * RB))[c4];
        }
        __syncthreads();
        // rbf_j per edge (column j of ee @ Wr + br), then m = xh[src]*rbf
        float m[EB];
#pragma unroll
        for (int e = 0; e < EB; ++e) m[e] = brj;
#pragma unroll
        for (int r4 = 0; r4 < 16; ++r4) {
            float4 w = wreg[r4];
#pragma unroll
            for (int e = 0; e < EB; ++e) {
                float4 a = *(const float4*)&eeL[e * RB + r4 * 4];
                m[e] += a.x * w.x + a.y * w.y + a.z * w.z + a.w * w.w;
            }
        }
#pragma unroll
        for (int e = 0; e < EB; ++e) {
            m[e] *= xh[(size_t)sSrc[e] * H3 + j];
            mst[e * H3 + j] = m[e];
        }
        __syncthreads();
        // accumulate into per-node LDS accumulators (no races: column j owned by thread j)
        if (j < H) {
#pragma unroll
            for (int e = 0; e < EB; ++e)
                if (sLd[e] >= 0) accdx[sLd[e] * H + j] += m[e];
        }
#pragma unroll
        for (int e = 0; e < EB; ++e) {
            if (sLd[e] >= 0) {
                float m2 = mst[e * H3 + H + hh] * INV_SQRT_3;
                float m3 = mst[e * H3 + 2 * H + hh];
                float vs = vec[(size_t)sSrc[e] * H3 + j];
                accdv[sLd[e] * H3 + j] += (vs * m2 + m3 * sEv[e][c]) * INV_SQRT_H;
            }
        }
        __syncthreads();
    }
    for (int i = j; i < NPB * H;  i += 384) dx_out[(size_t)n0 * H + i]    = accdx[i];
    for (int i = j; i < NPB * H3; i += 384) dvec_out[(size_t)n0 * H3 + i] = accdv[i];
}

// ---------------- D1: vec_mid/x_mid + vproj (Wv), vec1/vec_dot/vec2_norm ----
__global__ __launch_bounds__(256) void d1_kernel(
        const float* __restrict__ x, const float* __restrict__ vec,
        const float* __restrict__ Wv,
        float* __restrict__ B1, float* __restrict__ B2,
        float* __restrict__ B0, float* __restrict__ B3, float* __restrict__ B4) {
    __shared__ float vmL[8 * H3];
    __shared__ float WL[128 * 128];
    int tid = threadIdx.x;
    int n0 = blockIdx.x * 8;
    for (int i = tid; i < 8 * H3; i += 256) {
        float vm = vec[(size_t)n0 * H3 + i] + B1[(size_t)n0 * H3 + i];
        B1[(size_t)n0 * H3 + i] = vm;
        vmL[i] = vm;
    }
    for (int i = tid; i < 8 * H; i += 256) {
        float xm = (x[(size_t)n0 * H + i] + B2[(size_t)n0 * H + i]) * INV_SQRT_2;
        B2[(size_t)n0 * H + i] = xm;
    }
    int k = tid & 127, ng = tid >> 7;
    const float4* vmL4 = (const float4*)vmL;
    float a1[4][3], a2[4][3];
    __syncthreads();
#pragma unroll
    for (int q = 0; q < 16; ++q) {
        int i4 = tid + 256 * q;
        int h = i4 >> 5, c4 = i4 & 31;
        ((float4*)WL)[i4] = ((const float4*)(Wv + (size_t)h * 256))[c4];
    }
    __syncthreads();
#pragma unroll
    for (int n = 0; n < 4; ++n)
#pragma unroll
        for (int cc = 0; cc < 3; ++cc) a1[n][cc] = 0.f;
#pragma unroll 4
    for (int h4 = 0; h4 < 32; ++h4) {
        float w[4];
#pragma unroll
        for (int i = 0; i < 4; ++i) w[i] = WL[(h4 * 4 + i) * 128 + k];
#pragma unroll
        for (int n = 0; n < 4; ++n)
#pragma unroll
            for (int cc = 0; cc < 3; ++cc) {
                float4 a = vmL4[((ng * 4 + n) * 3 + cc) * 32 + h4];
                a1[n][cc] += a.x * w[0] + a.y * w[1] + a.z * w[2] + a.w * w[3];
            }
    }
#pragma unroll
    for (int n = 0; n < 4; ++n)
#pragma unroll
        for (int cc = 0; cc < 3; ++cc)
            B0[(size_t)(n0 + ng * 4 + n) * H3 + cc * H + k] = a1[n][cc];
    __syncthreads();
#pragma unroll
    for (int q = 0; q < 16; ++q) {
        int i4 = tid + 256 * q;
        int h = i4 >> 5, c4 = i4 & 31;
        ((float4*)WL)[i4] = ((const float4*)(Wv + (size_t)h * 256 + 128))[c4];
    }
    __syncthreads();
#pragma unroll
    for (int n = 0; n < 4; ++n)
#pragma unroll
        for (int cc = 0; cc < 3; ++cc) a2[n][cc] = 0.f;
#pragma unroll 4
    for (int h4 = 0; h4 < 32; ++h4) {
        float w[4];
#pragma unroll
        for (int i = 0; i < 4; ++i) w[i] = WL[(h4 * 4 + i) * 128 + k];
#pragma unroll
        for (int n = 0; n < 4; ++n)
#pragma unroll
            for (int cc = 0; cc < 3; ++cc) {
                float4 a = vmL4[((ng * 4 + n) * 3 + cc) * 32 + h4];
                a2[n][cc] += a.x * w[0] + a.y * w[1] + a.z * w[2] + a.w * w[3];
            }
    }
#pragma unroll
    for (int n = 0; n < 4; ++n) {
        int gn = n0 + ng * 4 + n;
        float dot = (a1[n][0] * a2[n][0] + a1[n][1] * a2[n][1] + a1[n][2] * a2[n][2]) * INV_SQRT_H;
        float nrm = sqrtf(a2[n][0] * a2[n][0] + a2[n][1] * a2[n][1] + a2[n][2] * a2[n][2] + 1e-8f);
        B3[(size_t)gn * H + k] = dot;
        B4[(size_t)gn * H + k] = nrm;
    }
}

// ---------------- D2a: u = scaled_silu([x_mid, vnorm] @ Wu1 + bu1) ----------
__global__ __launch_bounds__(256) void d2a_kernel(
        const float* __restrict__ Wu1, const float* __restrict__ bu1,
        const float* __restrict__ B2, float* __restrict__ B4) {
    __shared__ float catL[16 * 256];
    __shared__ float WL[128 * 128];
    int tid = threadIdx.x;
    int n0 = blockIdx.x * 16;
    for (int i = tid; i < 16 * 256; i += 256) {
        int n = i >> 8, kk = i & 255;
        catL[i] = (kk < 128) ? B2[(size_t)(n0 + n) * H + kk]
                             : B4[(size_t)(n0 + n) * H + kk - 128];
    }
    int c = tid & 127, ng = tid >> 7;
    float acc[8];
#pragma unroll
    for (int n = 0; n < 8; ++n) acc[n] = 0.f;
    const float4* catL4 = (const float4*)catL;
    for (int half = 0; half < 2; ++half) {
        __syncthreads();
#pragma unroll
        for (int q = 0; q < 16; ++q)
            ((float4*)WL)[tid + 256 * q] =
                ((const float4*)(Wu1 + (size_t)half * 128 * 128))[tid + 256 * q];
        __syncthreads();
#pragma unroll 4
        for (int k4 = 0; k4 < 32; ++k4) {
            float w[4];
#pragma unroll
            for (int i = 0; i < 4; ++i) w[i] = WL[(k4 * 4 + i) * 128 + c];
#pragma unroll
            for (int n = 0; n < 8; ++n) {
                float4 a = catL4[(ng * 8 + n) * 64 + half * 32 + k4];
                acc[n] += a.x * w[0] + a.y * w[1] + a.z * w[2] + a.w * w[3];
            }
        }
    }
    float bb = bu1[c];
#pragma unroll
    for (int n = 0; n < 8; ++n)
        B4[(size_t)(n0 + ng * 8 + n) * H + c] = scaled_silu(acc[n] + bb);
}

// ---------------- D2b: hh = u @ Wu2 + bu2, final outputs --------------------
__global__ __launch_bounds__(256) void d2b_kernel(
        const float* __restrict__ Wu2, const float* __restrict__ bu2,
        const float* __restrict__ B4, const float* __restrict__ B3,
        const float* __restrict__ B2, const float* __restrict__ B1,
        const float* __restrict__ B0, float* __restrict__ out) {
    __shared__ float uL[16 * 128];
    __shared__ float WL[128 * 128];
    __shared__ float stash[16 * 128];
    int tid = threadIdx.x;
    int n0 = blockIdx.x * 16;
#pragma unroll
    for (int q = 0; q < 2; ++q)
        ((float4*)uL)[tid + 256 * q] = ((const float4*)(B4 + (size_t)n0 * H))[tid + 256 * q];
    int c = tid & 127, ng = tid >> 7;
    const float4* uL4 = (const float4*)uL;
    float* out_vec = out;
    float* out_x = out + (size_t)NN * H3;
    for (int s = 0; s < 3; ++s) {
        __syncthreads();
#pragma unroll
        for (int q = 0; q < 16; ++q) {
            int i4 = tid + 256 * q;
            int kk = i4 >> 5, c4 = i4 & 31;
            ((float4*)WL)[i4] = ((const float4*)(Wu2 + (size_t)kk * H3 + s * H))[c4];
        }
        __syncthreads();
        float acc[8];
#pragma unroll
        for (int n = 0; n < 8; ++n) acc[n] = 0.f;
#pragma unroll 4
        for (int k4 = 0; k4 < 32; ++k4) {
            float w[4];
#pragma unroll
            for (int i = 0; i < 4; ++i) w[i] = WL[(k4 * 4 + i) * 128 + c];
#pragma unroll
            for (int n = 0; n < 8; ++n) {
                float4 a = uL4[(ng * 8 + n) * 32 + k4];
                acc[n] += a.x * w[0] + a.y * w[1] + a.z * w[2] + a.w * w[3];
            }
        }
        float bb = bu2[s * H + c];
        if (s == 0) {
#pragma unroll
            for (int n = 0; n < 8; ++n)
                stash[(ng * 8 + n) * 128 + c] = acc[n] + bb;
        } else if (s == 1) {
#pragma unroll
            for (int n = 0; n < 8; ++n) {
                int gn = n0 + ng * 8 + n;
                float xv2 = acc[n] + bb;
                float dx2 = (stash[(ng * 8 + n) * 128 + c] +
                             xv2 * B3[(size_t)gn * H + c]) * INV_SQRT_2;
                out_x[(size_t)gn * H + c] = B2[(size_t)gn * H + c] + dx2;
            }
        } else {
#pragma unroll
            for (int n = 0; n < 8; ++n) {
                int gn = n0 + ng * 8 + n;
                float xv3 = acc[n] + bb;
#pragma unroll
                for (int c3 = 0; c3 < 3; ++c3) {
                    size_t idx = (size_t)gn * H3 + c3 * H + c;
                    out_vec[idx] = B1[idx] + xv3 * B0[idx];
                }
            }
        }
    }
}

extern "C" void kernel_launch(void* const* d_in, const int* in_sizes, int n_in,
                              void* d_out, int out_size, void* d_ws, size_t ws_size,
                              hipStream_t stream) {
    const float* x    = (const float*)d_in[0];
    const float* vec  = (const float*)d_in[1];
    const int*   eidx = (const int*)d_in[2];
    const float* eemb = (const float*)d_in[3];
    const float* evec = (const float*)d_in[4];
    const float* lng  = (const float*)d_in[5];
    const float* lnb  = (const float*)d_in[6];
    const float* W1   = (const float*)d_in[7];
    const float* b1   = (const float*)d_in[8];
    const float* W2   = (const float*)d_in[9];
    const float* b2   = (const float*)d_in[10];
    const float* Wr   = (const float*)d_in[11];
    const float* br   = (const float*)d_in[12];
    const float* Wv   = (const float*)d_in[13];
    const float* Wu1  = (const float*)d_in[14];
    const float* bu1  = (const float*)d_in[15];
    const float* Wu2  = (const float*)d_in[16];
    const float* bu2  = (const float*)d_in[17];

    // workspace layout (fp32):
    // B0: N*384  xh -> vec1
    // B1: N*384  dvec -> vec_mid
    // B2: N*128  t(LN) -> dx -> x_mid
    // B3: N*128  h1 -> vec_dot
    // B4: N*128  [sort scratch: row_ptr/cursor/perm/srcs/dsts/ev_s] -> vnorm -> u
    float* B0 = (float*)d_ws;
    float* B1 = B0 + (size_t)NN * H3;
    float* B2 = B1 + (size_t)NN * H3;
    float* B3 = B2 + (size_t)NN * H;
    float* B4 = B3 + (size_t)NN * H;
    float* out = (float*)d_out;

    // sort scratch aliases B4 region (dead until d1_kernel): 12.9 MB of 16.8 MB
    int* row_ptr = (int*)B4;                 // 32769 (also the histogram, in place)
    int* cursor  = row_ptr + 32772;          // 32768
    int* perm    = cursor + 32768;           // NE
    int* srcs_s  = perm + NE;                // NE
    int* dsts_s  = srcs_s + NE;              // NE
    float* ev_s  = (float*)(dsts_s + NE);    // NE*3

    ln_kernel<<<NN / 4, 256, 0, stream>>>(x, lng, lnb, B2);
    g1_kernel<<<NN / 32, 256, 0, stream>>>(B2, W1, b1, B3);
    g2_kernel<<<NN / 32, 256, 0, stream>>>(B3, W2, b2, B0);
    // dst counting sort -> CSR
    hipMemsetAsync(row_ptr, 0, 32768 * sizeof(int), stream);
    hist_kernel<<<NE / 256, 256, 0, stream>>>(eidx, row_ptr);
    scan_kernel<<<1, 1024, 0, stream>>>(row_ptr, row_ptr, cursor);
    scatter_kernel<<<NE / 256, 256, 0, stream>>>(eidx, evec, cursor, perm, srcs_s, dsts_s, ev_s);
    // fused edge message + segment reduce (no global atomics)
    edge_csr_kernel<<<NN / NPB, 384, 0, stream>>>(row_ptr, perm, srcs_s, dsts_s, ev_s,
                                                  eemb, Wr, br, B0, vec, B2, B1);
    d1_kernel<<<NN / 8, 256, 0, stream>>>(x, vec, Wv, B1, B2, B0, B3, B4);
    d2a_kernel<<<NN / 16, 256, 0, stream>>>(Wu1, bu1, B2, B4);
    d2b_kernel<<<NN / 16, 256, 0, stream>>>(Wu2, bu2, B4, B3, B2, B1, B0, out);
}

// Round 3
// 1581.320 us; speedup vs baseline: 14.3041x; 1.6684x over previous
//
#include <hip/hip_runtime.h>
#include <cstdint>
#include <cstddef>

#define NN 32768
#define NE 524288
#define H  128
#define H3 384
#define RB 64
#define EB 16
#define NPB 4        // dst nodes per block in edge kernel
#define EEST 72      // padded LDS row stride (shorts) for ee tile
#define MSTRIDE 388  // padded LDS row stride (floats) for mst

#define INV_SQRT_3 0.5773502691896258f
#define INV_SQRT_H 0.08838834764831845f
#define INV_SQRT_2 0.7071067811865476f

typedef __attribute__((ext_vector_type(8))) short short8;
typedef __attribute__((ext_vector_type(4))) float f32x4;

__device__ __forceinline__ float scaled_silu(float v) {
    return v * (1.0f / 0.6f) / (1.0f + __expf(-v));
}

__device__ __forceinline__ short f2bf(float f) {
    uint32_t u = __float_as_uint(f);
    uint32_t r = (u + 0x7FFFu + ((u >> 16) & 1u)) >> 16;
    return (short)r;
}

// ---------------- LayerNorm: t = LN(x) --------------------------------------
__global__ __launch_bounds__(256) void ln_kernel(const float* __restrict__ x,
        const float* __restrict__ g, const float* __restrict__ b,
        float* __restrict__ t) {
    int row  = blockIdx.x * 4 + (threadIdx.x >> 6);
    int lane = threadIdx.x & 63;
    const float* xr = x + (size_t)row * H;
    float v0 = xr[lane], v1 = xr[lane + 64];
    float s = v0 + v1;
#pragma unroll
    for (int off = 32; off; off >>= 1) s += __shfl_xor(s, off, 64);
    float mu = s * (1.0f / 128.0f);
    float d0 = v0 - mu, d1 = v1 - mu;
    float q = d0 * d0 + d1 * d1;
#pragma unroll
    for (int off = 32; off; off >>= 1) q += __shfl_xor(q, off, 64);
    float rs = rsqrtf(q * (1.0f / 128.0f) + 1e-5f);
    float* tr = t + (size_t)row * H;
    tr[lane]      = d0 * rs * g[lane]      + b[lane];
    tr[lane + 64] = d1 * rs * g[lane + 64] + b[lane + 64];
}

// ---------------- G1: h1 = scaled_silu(t @ W1 + b1) -------------------------
__global__ __launch_bounds__(256) void g1_kernel(const float* __restrict__ t,
        const float* __restrict__ W1, const float* __restrict__ b1,
        float* __restrict__ h1) {
    __shared__ float WL[128 * 128];
    __shared__ float AL[32 * 128];
    int tid = threadIdx.x;
    int r0 = blockIdx.x * 32;
#pragma unroll
    for (int q = 0; q < 16; ++q)
        ((float4*)WL)[tid + 256 * q] = ((const float4*)W1)[tid + 256 * q];
#pragma unroll
    for (int q = 0; q < 4; ++q)
        ((float4*)AL)[tid + 256 * q] = ((const float4*)(t + (size_t)r0 * H))[tid + 256 * q];
    __syncthreads();
    int c2 = tid & 63, rg = tid >> 6;
    float acc0[8], acc1[8];
#pragma unroll
    for (int r = 0; r < 8; ++r) { acc0[r] = 0.f; acc1[r] = 0.f; }
    const float4* AL4 = (const float4*)AL;
#pragma unroll 4
    for (int k4 = 0; k4 < 32; ++k4) {
        float w0[4], w1[4];
#pragma unroll
        for (int i = 0; i < 4; ++i) {
            w0[i] = WL[(k4 * 4 + i) * 128 + c2];
            w1[i] = WL[(k4 * 4 + i) * 128 + c2 + 64];
        }
#pragma unroll
        for (int r = 0; r < 8; ++r) {
            float4 a = AL4[(rg * 8 + r) * 32 + k4];
            acc0[r] += a.x * w0[0] + a.y * w0[1] + a.z * w0[2] + a.w * w0[3];
            acc1[r] += a.x * w1[0] + a.y * w1[1] + a.z * w1[2] + a.w * w1[3];
        }
    }
    float bb0 = b1[c2], bb1 = b1[c2 + 64];
#pragma unroll
    for (int r = 0; r < 8; ++r) {
        int row = r0 + rg * 8 + r;
        h1[(size_t)row * H + c2]      = scaled_silu(acc0[r] + bb0);
        h1[(size_t)row * H + c2 + 64] = scaled_silu(acc1[r] + bb1);
    }
}

// ---------------- G2: xh = h1 @ W2 + b2 -------------------------------------
__global__ __launch_bounds__(256) void g2_kernel(const float* __restrict__ h1,
        const float* __restrict__ W2, const float* __restrict__ b2,
        float* __restrict__ xh) {
    __shared__ float WL[128 * 128];
    __shared__ float AL[32 * 128];
    int tid = threadIdx.x;
    int r0 = blockIdx.x * 32;
#pragma unroll
    for (int q = 0; q < 4; ++q)
        ((float4*)AL)[tid + 256 * q] = ((const float4*)(h1 + (size_t)r0 * H))[tid + 256 * q];
    int c2 = tid & 63, rg = tid >> 6;
    const float4* AL4 = (const float4*)AL;
    for (int s = 0; s < 3; ++s) {
        __syncthreads();
#pragma unroll
        for (int q = 0; q < 16; ++q) {
            int i4 = tid + 256 * q;
            int kk = i4 >> 5, c4 = i4 & 31;
            ((float4*)WL)[i4] = ((const float4*)(W2 + (size_t)kk * H3 + s * H))[c4];
        }
        __syncthreads();
        float acc0[8], acc1[8];
#pragma unroll
        for (int r = 0; r < 8; ++r) { acc0[r] = 0.f; acc1[r] = 0.f; }
#pragma unroll 4
        for (int k4 = 0; k4 < 32; ++k4) {
            float w0[4], w1[4];
#pragma unroll
            for (int i = 0; i < 4; ++i) {
                w0[i] = WL[(k4 * 4 + i) * 128 + c2];
                w1[i] = WL[(k4 * 4 + i) * 128 + c2 + 64];
            }
#pragma unroll
            for (int r = 0; r < 8; ++r) {
                float4 a = AL4[(rg * 8 + r) * 32 + k4];
                acc0[r] += a.x * w0[0] + a.y * w0[1] + a.z * w0[2] + a.w * w0[3];
                acc1[r] += a.x * w1[0] + a.y * w1[1] + a.z * w1[2] + a.w * w1[3];
            }
        }
        float bb0 = b2[s * H + c2], bb1 = b2[s * H + c2 + 64];
#pragma unroll
        for (int r = 0; r < 8; ++r) {
            int row = r0 + rg * 8 + r;
            xh[(size_t)row * H3 + s * H + c2]      = acc0[r] + bb0;
            xh[(size_t)row * H3 + s * H + c2 + 64] = acc1[r] + bb1;
        }
    }
}

// ---------------- Sort pass 1: histogram of dst -----------------------------
__global__ __launch_bounds__(256) void hist_kernel(const int* __restrict__ eidx,
        int* __restrict__ hist) {
    int e = blockIdx.x * 256 + threadIdx.x;
    atomicAdd(&hist[eidx[NE + e]], 1);
}

// ---------------- Sort pass 2: exclusive scan of 32768 counts ---------------
__global__ __launch_bounds__(1024) void scan_kernel(const int* __restrict__ hist,
        int* __restrict__ row_ptr, int* __restrict__ cursor) {
    __shared__ int sc[1024];
    int t = threadIdx.x;
    int base = t * 32;
    int v[32];
    int s = 0;
#pragma unroll
    for (int i = 0; i < 32; ++i) {
        int tmp = hist[base + i];
        v[i] = s;
        s += tmp;
    }
    sc[t] = s;
    __syncthreads();
    for (int off = 1; off < 1024; off <<= 1) {
        int a = sc[t];
        int b = (t >= off) ? sc[t - off] : 0;
        __syncthreads();
        sc[t] = a + b;
        __syncthreads();
    }
    int excl = sc[t] - s;
#pragma unroll
    for (int i = 0; i < 32; ++i) {
        int val = excl + v[i];
        row_ptr[base + i] = val;
        cursor[base + i] = val;
    }
    if (t == 0) row_ptr[32768] = NE;
}

// ---------------- Sort pass 3: scatter edges into dst-sorted order ----------
__global__ __launch_bounds__(256) void scatter_kernel(const int* __restrict__ eidx,
        const float* __restrict__ evec, int* __restrict__ cursor,
        int* __restrict__ perm, int* __restrict__ srcs_s, int* __restrict__ dsts_s,
        float* __restrict__ ev_s) {
    int e = blockIdx.x * 256 + threadIdx.x;
    int d = eidx[NE + e];
    int pos = atomicAdd(&cursor[d], 1);
    perm[pos]   = e;
    srcs_s[pos] = eidx[e];
    dsts_s[pos] = d;
    ev_s[pos * 3 + 0] = evec[e * 3 + 0];
    ev_s[pos * 3 + 1] = evec[e * 3 + 1];
    ev_s[pos * 3 + 2] = evec[e * 3 + 2];
}

// ---------------- Wr^T bf16 precompute: WrT16[n][k] = bf16(Wr[k][n]) --------
__global__ __launch_bounds__(256) void wrt_kernel(const float* __restrict__ Wr,
        short* __restrict__ WrT16) {
    int i = blockIdx.x * 256 + threadIdx.x;  // over 384*64
    int n = i >> 6, k = i & 63;
    WrT16[i] = f2bf(Wr[(size_t)k * H3 + n]);
}

// ---------------- Edge kernel (CSR + MFMA) ----------------------------------
// 384 threads = 6 waves; wave w owns output cols [64w, 64w+64).
// B (Wr^T) fragments live in 32 VGPRs for the whole kernel.
__global__ __launch_bounds__(384) void edge_mfma_kernel(
        const int* __restrict__ row_ptr, const int* __restrict__ perm,
        const int* __restrict__ srcs_s, const int* __restrict__ dsts_s,
        const float* __restrict__ ev_s, const float* __restrict__ eembed,
        const short* __restrict__ WrT16, const float* __restrict__ br,
        const float* __restrict__ xh, const float* __restrict__ vec,
        float* __restrict__ dx_out, float* __restrict__ dvec_out) {
    __shared__ float accdx[NPB * H];        // 2KB
    __shared__ float accdv[NPB * H3];       // 6KB
    __shared__ short eeL[EB * EEST];        // 2.25KB bf16 ee tile (padded rows)
    __shared__ float mst[EB * MSTRIDE];     // 24.8KB m tile (padded rows)
    __shared__ int   sSrc[EB];
    __shared__ int   sLd[EB];
    __shared__ float sEv[EB][3];
    int j = threadIdx.x;                    // 0..383
    int w = j >> 6, l = j & 63;
    int lm = l & 15, q = l >> 4;
    // preload loop-invariant B fragments + bias + slice scale
    short8 bfrag[4][2];
#pragma unroll
    for (int t = 0; t < 4; ++t)
#pragma unroll
        for (int hf = 0; hf < 2; ++hf)
            bfrag[t][hf] = *(const short8*)(WrT16 +
                ((size_t)(w * 64 + t * 16 + lm) * 64 + q * 8 + hf * 32));
    float brj[4];
#pragma unroll
    for (int t = 0; t < 4; ++t) brj[t] = br[w * 64 + t * 16 + lm];
    float scale = (w < 2) ? 1.0f : ((w < 4) ? (INV_SQRT_3 * INV_SQRT_H) : INV_SQRT_H);
    int n0 = blockIdx.x * NPB;
    for (int i = j; i < NPB * H;  i += 384) accdx[i] = 0.f;
    for (int i = j; i < NPB * H3; i += 384) accdv[i] = 0.f;
    int ib = row_ptr[n0], ie = row_ptr[n0 + NPB];
    int c = j >> 7, hh = j & 127;
    __syncthreads();
    for (int base = ib; base < ie; base += EB) {
        int cnt = min(EB, ie - base);
        // ---- stage: ee tile (bf16), edge meta ----
        if (j < 256) {
            int e = j >> 4, c4 = j & 15;
            int i = base + ((e < cnt) ? e : 0);
            int p = perm[i];
            float4 a = ((const float4*)(eembed + (size_t)p * RB))[c4];
            short4 b4;
            b4.x = f2bf(a.x); b4.y = f2bf(a.y); b4.z = f2bf(a.z); b4.w = f2bf(a.w);
            *(short4*)(eeL + e * EEST + c4 * 4) = b4;
        }
        if (j < EB) {
            int i = base + ((j < cnt) ? j : 0);
            sSrc[j] = srcs_s[i];
            sLd[j]  = dsts_s[i] - n0;
            sEv[j][0] = ev_s[(size_t)i * 3 + 0];
            sEv[j][1] = ev_s[(size_t)i * 3 + 1];
            sEv[j][2] = ev_s[(size_t)i * 3 + 2];
        }
        __syncthreads();
        // ---- MFMA: rbf tile = ee @ Wr (16 edges x 64 cols per wave) ----
        short8 a0 = *(const short8*)(eeL + lm * EEST + q * 8);
        short8 a1 = *(const short8*)(eeL + lm * EEST + 32 + q * 8);
        f32x4 d[4];
#pragma unroll
        for (int t = 0; t < 4; ++t) {
            d[t] = __builtin_amdgcn_mfma_f32_16x16x32_bf16(a0, bfrag[t][0],
                       (f32x4){0.f, 0.f, 0.f, 0.f}, 0, 0, 0);
            d[t] = __builtin_amdgcn_mfma_f32_16x16x32_bf16(a1, bfrag[t][1], d[t], 0, 0, 0);
        }
        // ---- epilogue: m = (rbf + br) * xh[src] * slice_scale -> mst ----
#pragma unroll
        for (int r = 0; r < 4; ++r) {
            int e = q * 4 + r;
            const float* xr = xh + (size_t)sSrc[e] * H3 + w * 64;
#pragma unroll
            for (int t = 0; t < 4; ++t) {
                float m = (d[t][r] + brj[t]) * xr[t * 16 + lm] * scale;
                mst[e * MSTRIDE + w * 64 + t * 16 + lm] = m;
            }
        }
        __syncthreads();
        // ---- accumulate (register acc, flush on dst-node change) ----
        int cur = -1; float dva = 0.f, dxa = 0.f;
#pragma unroll 4
        for (int e = 0; e < cnt; ++e) {
            int ld = sLd[e];
            if (ld != cur) {
                if (cur >= 0) {
                    accdv[cur * H3 + j] += dva;
                    if (j < H) accdx[cur * H + j] += dxa;
                }
                cur = ld; dva = 0.f; dxa = 0.f;
            }
            float m2 = mst[e * MSTRIDE + H + hh];       // pre-scaled
            float m3 = mst[e * MSTRIDE + 2 * H + hh];   // pre-scaled
            float vs = vec[(size_t)sSrc[e] * H3 + j];
            dva += vs * m2 + m3 * sEv[e][c];
            if (j < H) dxa += mst[e * MSTRIDE + j];
        }
        if (cur >= 0) {
            accdv[cur * H3 + j] += dva;
            if (j < H) accdx[cur * H + j] += dxa;
        }
        __syncthreads();
    }
    for (int i = j; i < NPB * H;  i += 384) dx_out[(size_t)n0 * H + i]    = accdx[i];
    for (int i = j; i < NPB * H3; i += 384) dvec_out[(size_t)n0 * H3 + i] = accdv[i];
}

// ---------------- D1: vec_mid/x_mid + vproj (Wv), vec1/vec_dot/vec2_norm ----
__global__ __launch_bounds__(256) void d1_kernel(
        const float* __restrict__ x, const float* __restrict__ vec,
        const float* __restrict__ Wv,
        float* __restrict__ B1, float* __restrict__ B2,
        float* __restrict__ B0, float* __restrict__ B3, float* __restrict__ B4) {
    __shared__ float vmL[8 * H3];
    __shared__ float WL[128 * 128];
    int tid = threadIdx.x;
    int n0 = blockIdx.x * 8;
    for (int i = tid; i < 8 * H3; i += 256) {
        float vm = vec[(size_t)n0 * H3 + i] + B1[(size_t)n0 * H3 + i];
        B1[(size_t)n0 * H3 + i] = vm;
        vmL[i] = vm;
    }
    for (int i = tid; i < 8 * H; i += 256) {
        float xm = (x[(size_t)n0 * H + i] + B2[(size_t)n0 * H + i]) * INV_SQRT_2;
        B2[(size_t)n0 * H + i] = xm;
    }
    int k = tid & 127, ng = tid >> 7;
    const float4* vmL4 = (const float4*)vmL;
    float a1[4][3], a2[4][3];
    __syncthreads();
#pragma unroll
    for (int q = 0; q < 16; ++q) {
        int i4 = tid + 256 * q;
        int h = i4 >> 5, c4 = i4 & 31;
        ((float4*)WL)[i4] = ((const float4*)(Wv + (size_t)h * 256))[c4];
    }
    __syncthreads();
#pragma unroll
    for (int n = 0; n < 4; ++n)
#pragma unroll
        for (int cc = 0; cc < 3; ++cc) a1[n][cc] = 0.f;
#pragma unroll 4
    for (int h4 = 0; h4 < 32; ++h4) {
        float w[4];
#pragma unroll
        for (int i = 0; i < 4; ++i) w[i] = WL[(h4 * 4 + i) * 128 + k];
#pragma unroll
        for (int n = 0; n < 4; ++n)
#pragma unroll
            for (int cc = 0; cc < 3; ++cc) {
                float4 a = vmL4[((ng * 4 + n) * 3 + cc) * 32 + h4];
                a1[n][cc] += a.x * w[0] + a.y * w[1] + a.z * w[2] + a.w * w[3];
            }
    }
#pragma unroll
    for (int n = 0; n < 4; ++n)
#pragma unroll
        for (int cc = 0; cc < 3; ++cc)
            B0[(size_t)(n0 + ng * 4 + n) * H3 + cc * H + k] = a1[n][cc];
    __syncthreads();
#pragma unroll
    for (int q = 0; q < 16; ++q) {
        int i4 = tid + 256 * q;
        int h = i4 >> 5, c4 = i4 & 31;
        ((float4*)WL)[i4] = ((const float4*)(Wv + (size_t)h * 256 + 128))[c4];
    }
    __syncthreads();
#pragma unroll
    for (int n = 0; n < 4; ++n)
#pragma unroll
        for (int cc = 0; cc < 3; ++cc) a2[n][cc] = 0.f;
#pragma unroll 4
    for (int h4 = 0; h4 < 32; ++h4) {
        float w[4];
#pragma unroll
        for (int i = 0; i < 4; ++i) w[i] = WL[(h4 * 4 + i) * 128 + k];
#pragma unroll
        for (int n = 0; n < 4; ++n)
#pragma unroll
            for (int cc = 0; cc < 3; ++cc) {
                float4 a = vmL4[((ng * 4 + n) * 3 + cc) * 32 + h4];
                a2[n][cc] += a.x * w[0] + a.y * w[1] + a.z * w[2] + a.w * w[3];
            }
    }
#pragma unroll
    for (int n = 0; n < 4; ++n) {
        int gn = n0 + ng * 4 + n;
        float dot = (a1[n][0] * a2[n][0] + a1[n][1] * a2[n][1] + a1[n][2] * a2[n][2]) * INV_SQRT_H;
        float nrm = sqrtf(a2[n][0] * a2[n][0] + a2[n][1] * a2[n][1] + a2[n][2] * a2[n][2] + 1e-8f);
        B3[(size_t)gn * H + k] = dot;
        B4[(size_t)gn * H + k] = nrm;
    }
}

// ---------------- D2a: u = scaled_silu([x_mid, vnorm] @ Wu1 + bu1) ----------
__global__ __launch_bounds__(256) void d2a_kernel(
        const float* __restrict__ Wu1, const float* __restrict__ bu1,
        const float* __restrict__ B2, float* __restrict__ B4) {
    __shared__ float catL[16 * 256];
    __shared__ float WL[128 * 128];
    int tid = threadIdx.x;
    int n0 = blockIdx.x * 16;
    for (int i = tid; i < 16 * 256; i += 256) {
        int n = i >> 8, kk = i & 255;
        catL[i] = (kk < 128) ? B2[(size_t)(n0 + n) * H + kk]
                             : B4[(size_t)(n0 + n) * H + kk - 128];
    }
    int c = tid & 127, ng = tid >> 7;
    float acc[8];
#pragma unroll
    for (int n = 0; n < 8; ++n) acc[n] = 0.f;
    const float4* catL4 = (const float4*)catL;
    for (int half = 0; half < 2; ++half) {
        __syncthreads();
#pragma unroll
        for (int q = 0; q < 16; ++q)
            ((float4*)WL)[tid + 256 * q] =
                ((const float4*)(Wu1 + (size_t)half * 128 * 128))[tid + 256 * q];
        __syncthreads();
#pragma unroll 4
        for (int k4 = 0; k4 < 32; ++k4) {
            float w[4];
#pragma unroll
            for (int i = 0; i < 4; ++i) w[i] = WL[(k4 * 4 + i) * 128 + c];
#pragma unroll
            for (int n = 0; n < 8; ++n) {
                float4 a = catL4[(ng * 8 + n) * 64 + half * 32 + k4];
                acc[n] += a.x * w[0] + a.y * w[1] + a.z * w[2] + a.w * w[3];
            }
        }
    }
    float bb = bu1[c];
#pragma unroll
    for (int n = 0; n < 8; ++n)
        B4[(size_t)(n0 + ng * 8 + n) * H + c] = scaled_silu(acc[n] + bb);
}

// ---------------- D2b: hh = u @ Wu2 + bu2, final outputs --------------------
__global__ __launch_bounds__(256) void d2b_kernel(
        const float* __restrict__ Wu2, const float* __restrict__ bu2,
        const float* __restrict__ B4, const float* __restrict__ B3,
        const float* __restrict__ B2, const float* __restrict__ B1,
        const float* __restrict__ B0, float* __restrict__ out) {
    __shared__ float uL[16 * 128];
    __shared__ float WL[128 * 128];
    __shared__ float stash[16 * 128];
    int tid = threadIdx.x;
    int n0 = blockIdx.x * 16;
#pragma unroll
    for (int q = 0; q < 2; ++q)
        ((float4*)uL)[tid + 256 * q] = ((const float4*)(B4 + (size_t)n0 * H))[tid + 256 * q];
    int c = tid & 127, ng = tid >> 7;
    const float4* uL4 = (const float4*)uL;
    float* out_vec = out;
    float* out_x = out + (size_t)NN * H3;
    for (int s = 0; s < 3; ++s) {
        __syncthreads();
#pragma unroll
        for (int q = 0; q < 16; ++q) {
            int i4 = tid + 256 * q;
            int kk = i4 >> 5, c4 = i4 & 31;
            ((float4*)WL)[i4] = ((const float4*)(Wu2 + (size_t)kk * H3 + s * H))[c4];
        }
        __syncthreads();
        float acc[8];
#pragma unroll
        for (int n = 0; n < 8; ++n) acc[n] = 0.f;
#pragma unroll 4
        for (int k4 = 0; k4 < 32; ++k4) {
            float w[4];
#pragma unroll
            for (int i = 0; i < 4; ++i) w[i] = WL[(k4 * 4 + i) * 128 + c];
#pragma unroll
            for (int n = 0; n < 8; ++n) {
                float4 a = uL4[(ng * 8 + n) * 32 + k4];
                acc[n] += a.x * w[0] + a.y * w[1] + a.z * w[2] + a.w * w[3];
            }
        }
        float bb = bu2[s * H + c];
        if (s == 0) {
#pragma unroll
            for (int n = 0; n < 8; ++n)
                stash[(ng * 8 + n) * 128 + c] = acc[n] + bb;
        } else if (s == 1) {
#pragma unroll
            for (int n = 0; n < 8; ++n) {
                int gn = n0 + ng * 8 + n;
                float xv2 = acc[n] + bb;
                float dx2 = (stash[(ng * 8 + n) * 128 + c] +
                             xv2 * B3[(size_t)gn * H + c]) * INV_SQRT_2;
                out_x[(size_t)gn * H + c] = B2[(size_t)gn * H + c] + dx2;
            }
        } else {
#pragma unroll
            for (int n = 0; n < 8; ++n) {
                int gn = n0 + ng * 8 + n;
                float xv3 = acc[n] + bb;
#pragma unroll
                for (int c3 = 0; c3 < 3; ++c3) {
                    size_t idx = (size_t)gn * H3 + c3 * H + c;
                    out_vec[idx] = B1[idx] + xv3 * B0[idx];
                }
            }
        }
    }
}

extern "C" void kernel_launch(void* const* d_in, const int* in_sizes, int n_in,
                              void* d_out, int out_size, void* d_ws, size_t ws_size,
                              hipStream_t stream) {
    const float* x    = (const float*)d_in[0];
    const float* vec  = (const float*)d_in[1];
    const int*   eidx = (const int*)d_in[2];
    const float* eemb = (const float*)d_in[3];
    const float* evec = (const float*)d_in[4];
    const float* lng  = (const float*)d_in[5];
    const float* lnb  = (const float*)d_in[6];
    const float* W1   = (const float*)d_in[7];
    const float* b1   = (const float*)d_in[8];
    const float* W2   = (const float*)d_in[9];
    const float* b2   = (const float*)d_in[10];
    const float* Wr   = (const float*)d_in[11];
    const float* br   = (const float*)d_in[12];
    const float* Wv   = (const float*)d_in[13];
    const float* Wu1  = (const float*)d_in[14];
    const float* bu1  = (const float*)d_in[15];
    const float* Wu2  = (const float*)d_in[16];
    const float* bu2  = (const float*)d_in[17];

    // workspace layout (fp32):
    // B0: N*384  xh -> vec1
    // B1: N*384  dvec -> vec_mid
    // B2: N*128  t(LN) -> dx -> x_mid
    // B3: N*128  h1 -> vec_dot
    // B4: N*128  [sort scratch + WrT16] -> vnorm -> u
    float* B0 = (float*)d_ws;
    float* B1 = B0 + (size_t)NN * H3;
    float* B2 = B1 + (size_t)NN * H3;
    float* B3 = B2 + (size_t)NN * H;
    float* B4 = B3 + (size_t)NN * H;
    float* out = (float*)d_out;

    int* row_ptr = (int*)B4;                 // 32769 (also the histogram, in place)
    int* cursor  = row_ptr + 32772;          // 32768
    int* perm    = cursor + 32768;           // NE
    int* srcs_s  = perm + NE;                // NE
    int* dsts_s  = srcs_s + NE;              // NE
    float* ev_s  = (float*)(dsts_s + NE);    // NE*3
    short* WrT16 = (short*)(ev_s + (size_t)NE * 3);  // 384*64 bf16

    ln_kernel<<<NN / 4, 256, 0, stream>>>(x, lng, lnb, B2);
    g1_kernel<<<NN / 32, 256, 0, stream>>>(B2, W1, b1, B3);
    g2_kernel<<<NN / 32, 256, 0, stream>>>(B3, W2, b2, B0);
    // dst counting sort -> CSR
    hipMemsetAsync(row_ptr, 0, 32768 * sizeof(int), stream);
    hist_kernel<<<NE / 256, 256, 0, stream>>>(eidx, row_ptr);
    scan_kernel<<<1, 1024, 0, stream>>>(row_ptr, row_ptr, cursor);
    scatter_kernel<<<NE / 256, 256, 0, stream>>>(eidx, evec, cursor, perm, srcs_s, dsts_s, ev_s);
    wrt_kernel<<<(H3 * RB) / 256, 256, 0, stream>>>(Wr, WrT16);
    // fused edge message + segment reduce (MFMA rbf, no global atomics)
    edge_mfma_kernel<<<NN / NPB, 384, 0, stream>>>(row_ptr, perm, srcs_s, dsts_s, ev_s,
                                                   eemb, WrT16, br, B0, vec, B2, B1);
    d1_kernel<<<NN / 8, 256, 0, stream>>>(x, vec, Wv, B1, B2, B0, B3, B4);
    d2a_kernel<<<NN / 16, 256, 0, stream>>>(Wu1, bu1, B2, B4);
    d2b_kernel<<<NN / 16, 256, 0, stream>>>(Wu2, bu2, B4, B3, B2, B1, B0, out);
}

// Round 4
// 1124.560 us; speedup vs baseline: 20.1139x; 1.4062x over previous
//
#include <hip/hip_runtime.h>
#include <cstdint>
#include <cstddef>

#define NN 32768
#define NE 524288
#define H  128
#define H3 384
#define RB 64
#define EB 16
#define NPB 4        // dst nodes per block in edge kernel
#define EEST 72      // padded LDS row stride (shorts) for ee tile
#define MSTRIDE 388  // padded LDS row stride (floats) for mst
#define AST 136      // padded LDS row stride (shorts) for 128-wide bf16 tiles

#define INV_SQRT_3 0.5773502691896258f
#define INV_SQRT_H 0.08838834764831845f
#define INV_SQRT_2 0.7071067811865476f

typedef __attribute__((ext_vector_type(8))) short short8;
typedef __attribute__((ext_vector_type(4))) float f32x4;

__device__ __forceinline__ float scaled_silu(float v) {
    return v * (1.0f / 0.6f) / (1.0f + __expf(-v));
}
__device__ __forceinline__ short f2bf(float f) {
    uint32_t u = __float_as_uint(f);
    uint32_t r = (u + 0x7FFFu + ((u >> 16) & 1u)) >> 16;
    return (short)r;
}
__device__ __forceinline__ float bf2f(short s) {
    return __uint_as_float(((uint32_t)(uint16_t)s) << 16);
}

// ---------------- weight transpose+bf16: WT[m][k] = bf16(W[k][m]) -----------
__global__ __launch_bounds__(256) void cvtT_kernel(const float* __restrict__ W,
        short* __restrict__ WT, int K, int M) {
    int i = blockIdx.x * 256 + threadIdx.x;  // i < K*M
    int k = i / M, m = i % M;
    WT[(size_t)m * K + k] = f2bf(W[(size_t)k * M + m]);
}

// ---------------- vec -> bf16 copy ------------------------------------------
__global__ __launch_bounds__(256) void veccvt_kernel(const float* __restrict__ v,
        short* __restrict__ vb) {
    int i = blockIdx.x * 256 + threadIdx.x;  // over N*H3/4
    float4 a = ((const float4*)v)[i];
    short4 s4; s4.x = f2bf(a.x); s4.y = f2bf(a.y); s4.z = f2bf(a.z); s4.w = f2bf(a.w);
    ((short4*)vb)[i] = s4;
}

// ---------------- LayerNorm: t = LN(x) --------------------------------------
__global__ __launch_bounds__(256) void ln_kernel(const float* __restrict__ x,
        const float* __restrict__ g, const float* __restrict__ b,
        float* __restrict__ t) {
    int row  = blockIdx.x * 4 + (threadIdx.x >> 6);
    int lane = threadIdx.x & 63;
    const float* xr = x + (size_t)row * H;
    float v0 = xr[lane], v1 = xr[lane + 64];
    float s = v0 + v1;
#pragma unroll
    for (int off = 32; off; off >>= 1) s += __shfl_xor(s, off, 64);
    float mu = s * (1.0f / 128.0f);
    float d0 = v0 - mu, d1 = v1 - mu;
    float q = d0 * d0 + d1 * d1;
#pragma unroll
    for (int off = 32; off; off >>= 1) q += __shfl_xor(q, off, 64);
    float rs = rsqrtf(q * (1.0f / 128.0f) + 1e-5f);
    float* tr = t + (size_t)row * H;
    tr[lane]      = d0 * rs * g[lane]      + b[lane];
    tr[lane + 64] = d1 * rs * g[lane + 64] + b[lane + 64];
}

// ---------------- G1: h1_bf = bf16(ssilu(t @ W1 + b1))  [N,128]x[128,128] ---
__global__ __launch_bounds__(256) void g1_mfma(const float* __restrict__ t,
        const short* __restrict__ W1T, const float* __restrict__ b1,
        short* __restrict__ h1_bf) {
    __shared__ short A_l[64 * AST];
    __shared__ short B_l[128 * AST];
    int tid = threadIdx.x;
    int w = tid >> 6, l = tid & 63, lm = l & 15, q = l >> 4;
    int r0 = blockIdx.x * 64;
    const float4* ag = (const float4*)(t + (size_t)r0 * H);
#pragma unroll
    for (int i = 0; i < 8; ++i) {
        int idx = tid + 256 * i;
        float4 a = ag[idx];
        int row = idx >> 5, c4 = idx & 31;
        short4 s4; s4.x = f2bf(a.x); s4.y = f2bf(a.y); s4.z = f2bf(a.z); s4.w = f2bf(a.w);
        *(short4*)&A_l[row * AST + c4 * 4] = s4;
    }
    const short8* wg = (const short8*)W1T;
#pragma unroll
    for (int i = 0; i < 8; ++i) {
        int idx = tid + 256 * i;
        int row = idx >> 4, c8 = idx & 15;
        *(short8*)&B_l[row * AST + c8 * 8] = wg[idx];
    }
    __syncthreads();
    short8 bf[2][4];
#pragma unroll
    for (int c = 0; c < 2; ++c)
#pragma unroll
        for (int ks = 0; ks < 4; ++ks)
            bf[c][ks] = *(const short8*)&B_l[((2 * w + c) * 16 + lm) * AST + ks * 32 + q * 8];
    f32x4 acc[4][2];
#pragma unroll
    for (int rt = 0; rt < 4; ++rt) { acc[rt][0] = (f32x4){0.f,0.f,0.f,0.f}; acc[rt][1] = (f32x4){0.f,0.f,0.f,0.f}; }
#pragma unroll
    for (int ks = 0; ks < 4; ++ks)
#pragma unroll
        for (int rt = 0; rt < 4; ++rt) {
            short8 a = *(const short8*)&A_l[(rt * 16 + lm) * AST + ks * 32 + q * 8];
            acc[rt][0] = __builtin_amdgcn_mfma_f32_16x16x32_bf16(a, bf[0][ks], acc[rt][0], 0, 0, 0);
            acc[rt][1] = __builtin_amdgcn_mfma_f32_16x16x32_bf16(a, bf[1][ks], acc[rt][1], 0, 0, 0);
        }
#pragma unroll
    for (int c = 0; c < 2; ++c) {
        int col = (2 * w + c) * 16 + lm;
        float bb = b1[col];
#pragma unroll
        for (int rt = 0; rt < 4; ++rt)
#pragma unroll
            for (int r = 0; r < 4; ++r) {
                int R = r0 + rt * 16 + q * 4 + r;
                h1_bf[(size_t)R * H + col] = f2bf(scaled_silu(acc[rt][c][r] + bb));
            }
    }
}

// ---------------- G2: xh_bf = bf16(h1 @ W2 + b2)  [N,128]x[128,384] ---------
__global__ __launch_bounds__(256) void g2_mfma(const short* __restrict__ h1_bf,
        const short* __restrict__ W2T, const float* __restrict__ b2,
        short* __restrict__ xh_bf) {
    __shared__ short A_l[64 * AST];
    __shared__ short B_l[128 * AST];
    int tid = threadIdx.x;
    int w = tid >> 6, l = tid & 63, lm = l & 15, q = l >> 4;
    int r0 = blockIdx.x * 64;
    const short8* ag = (const short8*)(h1_bf + (size_t)r0 * H);
#pragma unroll
    for (int i = 0; i < 4; ++i) {
        int idx = tid + 256 * i;
        int row = idx >> 4, c8 = idx & 15;
        *(short8*)&A_l[row * AST + c8 * 8] = ag[idx];
    }
    for (int s = 0; s < 3; ++s) {
        __syncthreads();
        const short8* wg = (const short8*)(W2T + (size_t)s * 128 * 128);
#pragma unroll
        for (int i = 0; i < 8; ++i) {
            int idx = tid + 256 * i;
            int row = idx >> 4, c8 = idx & 15;
            *(short8*)&B_l[row * AST + c8 * 8] = wg[idx];
        }
        __syncthreads();
        short8 bf[2][4];
#pragma unroll
        for (int c = 0; c < 2; ++c)
#pragma unroll
            for (int ks = 0; ks < 4; ++ks)
                bf[c][ks] = *(const short8*)&B_l[((2 * w + c) * 16 + lm) * AST + ks * 32 + q * 8];
        f32x4 acc[4][2];
#pragma unroll
        for (int rt = 0; rt < 4; ++rt) { acc[rt][0] = (f32x4){0.f,0.f,0.f,0.f}; acc[rt][1] = (f32x4){0.f,0.f,0.f,0.f}; }
#pragma unroll
        for (int ks = 0; ks < 4; ++ks)
#pragma unroll
            for (int rt = 0; rt < 4; ++rt) {
                short8 a = *(const short8*)&A_l[(rt * 16 + lm) * AST + ks * 32 + q * 8];
                acc[rt][0] = __builtin_amdgcn_mfma_f32_16x16x32_bf16(a, bf[0][ks], acc[rt][0], 0, 0, 0);
                acc[rt][1] = __builtin_amdgcn_mfma_f32_16x16x32_bf16(a, bf[1][ks], acc[rt][1], 0, 0, 0);
            }
#pragma unroll
        for (int c = 0; c < 2; ++c) {
            int col = (2 * w + c) * 16 + lm;
            float bb = b2[s * H + col];
#pragma unroll
            for (int rt = 0; rt < 4; ++rt)
#pragma unroll
                for (int r = 0; r < 4; ++r) {
                    int R = r0 + rt * 16 + q * 4 + r;
                    xh_bf[(size_t)R * H3 + s * H + col] = f2bf(acc[rt][c][r] + bb);
                }
        }
    }
}

// ---------------- Sort pass 1: histogram of dst -----------------------------
__global__ __launch_bounds__(256) void hist_kernel(const int* __restrict__ eidx,
        int* __restrict__ hist) {
    int e = blockIdx.x * 256 + threadIdx.x;
    atomicAdd(&hist[eidx[NE + e]], 1);
}

// ---------------- Sort pass 2: exclusive scan of 32768 counts ---------------
__global__ __launch_bounds__(1024) void scan_kernel(const int* __restrict__ hist,
        int* __restrict__ row_ptr, int* __restrict__ cursor) {
    __shared__ int sc[1024];
    int t = threadIdx.x;
    int base = t * 32;
    int v[32];
    int s = 0;
#pragma unroll
    for (int i = 0; i < 32; ++i) {
        int tmp = hist[base + i];
        v[i] = s;
        s += tmp;
    }
    sc[t] = s;
    __syncthreads();
    for (int off = 1; off < 1024; off <<= 1) {
        int a = sc[t];
        int b = (t >= off) ? sc[t - off] : 0;
        __syncthreads();
        sc[t] = a + b;
        __syncthreads();
    }
    int excl = sc[t] - s;
#pragma unroll
    for (int i = 0; i < 32; ++i) {
        int val = excl + v[i];
        row_ptr[base + i] = val;
        cursor[base + i] = val;
    }
    if (t == 0) row_ptr[32768] = NE;
}

// ---------------- Sort pass 3: scatter edges into dst-sorted order ----------
__global__ __launch_bounds__(256) void scatter_kernel(const int* __restrict__ eidx,
        const float* __restrict__ evec, int* __restrict__ cursor,
        int* __restrict__ perm, int* __restrict__ srcs_s, int* __restrict__ dsts_s,
        float* __restrict__ ev_s) {
    int e = blockIdx.x * 256 + threadIdx.x;
    int d = eidx[NE + e];
    int pos = atomicAdd(&cursor[d], 1);
    perm[pos]   = e;
    srcs_s[pos] = eidx[e];
    dsts_s[pos] = d;
    ev_s[pos * 3 + 0] = evec[e * 3 + 0];
    ev_s[pos * 3 + 1] = evec[e * 3 + 1];
    ev_s[pos * 3 + 2] = evec[e * 3 + 2];
}

// ---------------- Wr^T bf16 precompute --------------------------------------
__global__ __launch_bounds__(256) void wrt_kernel(const float* __restrict__ Wr,
        short* __restrict__ WrT16) {
    int i = blockIdx.x * 256 + threadIdx.x;  // over 384*64
    int n = i >> 6, k = i & 63;
    WrT16[i] = f2bf(Wr[(size_t)k * H3 + n]);
}

// ---------------- Edge kernel (CSR + MFMA, bf16 gathers) --------------------
__global__ __launch_bounds__(384) void edge_mfma_kernel(
        const int* __restrict__ row_ptr, const int* __restrict__ perm,
        const int* __restrict__ srcs_s, const int* __restrict__ dsts_s,
        const float* __restrict__ ev_s, const float* __restrict__ eembed,
        const short* __restrict__ WrT16, const float* __restrict__ br,
        const short* __restrict__ xh_bf, const short* __restrict__ vec_bf,
        float* __restrict__ dx_out, float* __restrict__ dvec_out) {
    __shared__ float accdx[NPB * H];
    __shared__ float accdv[NPB * H3];
    __shared__ short eeL[EB * EEST];
    __shared__ float mst[EB * MSTRIDE];
    __shared__ int   sSrc[EB];
    __shared__ int   sLd[EB];
    __shared__ float sEv[EB][3];
    int j = threadIdx.x;
    int w = j >> 6, l = j & 63;
    int lm = l & 15, q = l >> 4;
    short8 bfrag[4][2];
#pragma unroll
    for (int t = 0; t < 4; ++t)
#pragma unroll
        for (int hf = 0; hf < 2; ++hf)
            bfrag[t][hf] = *(const short8*)(WrT16 +
                ((size_t)(w * 64 + t * 16 + lm) * 64 + q * 8 + hf * 32));
    float brj[4];
#pragma unroll
    for (int t = 0; t < 4; ++t) brj[t] = br[w * 64 + t * 16 + lm];
    float scale = (w < 2) ? 1.0f : ((w < 4) ? (INV_SQRT_3 * INV_SQRT_H) : INV_SQRT_H);
    int n0 = blockIdx.x * NPB;
    for (int i = j; i < NPB * H;  i += 384) accdx[i] = 0.f;
    for (int i = j; i < NPB * H3; i += 384) accdv[i] = 0.f;
    int ib = row_ptr[n0], ie = row_ptr[n0 + NPB];
    int c = j >> 7, hh = j & 127;
    __syncthreads();
    for (int base = ib; base < ie; base += EB) {
        int cnt = min(EB, ie - base);
        if (j < 256) {
            int e = j >> 4, c4 = j & 15;
            int i = base + ((e < cnt) ? e : 0);
            int p = perm[i];
            float4 a = ((const float4*)(eembed + (size_t)p * RB))[c4];
            short4 b4;
            b4.x = f2bf(a.x); b4.y = f2bf(a.y); b4.z = f2bf(a.z); b4.w = f2bf(a.w);
            *(short4*)(eeL + e * EEST + c4 * 4) = b4;
        }
        if (j < EB) {
            int i = base + ((j < cnt) ? j : 0);
            sSrc[j] = srcs_s[i];
            sLd[j]  = dsts_s[i] - n0;
            sEv[j][0] = ev_s[(size_t)i * 3 + 0];
            sEv[j][1] = ev_s[(size_t)i * 3 + 1];
            sEv[j][2] = ev_s[(size_t)i * 3 + 2];
        }
        __syncthreads();
        short8 a0 = *(const short8*)(eeL + lm * EEST + q * 8);
        short8 a1 = *(const short8*)(eeL + lm * EEST + 32 + q * 8);
        f32x4 d[4];
#pragma unroll
        for (int t = 0; t < 4; ++t) {
            d[t] = __builtin_amdgcn_mfma_f32_16x16x32_bf16(a0, bfrag[t][0],
                       (f32x4){0.f, 0.f, 0.f, 0.f}, 0, 0, 0);
            d[t] = __builtin_amdgcn_mfma_f32_16x16x32_bf16(a1, bfrag[t][1], d[t], 0, 0, 0);
        }
#pragma unroll
        for (int r = 0; r < 4; ++r) {
            int e = q * 4 + r;
            const short* xr = xh_bf + (size_t)sSrc[e] * H3 + w * 64;
#pragma unroll
            for (int t = 0; t < 4; ++t) {
                float m = (d[t][r] + brj[t]) * bf2f(xr[t * 16 + lm]) * scale;
                mst[e * MSTRIDE + w * 64 + t * 16 + lm] = m;
            }
        }
        __syncthreads();
        int cur = -1; float dva = 0.f, dxa = 0.f;
#pragma unroll 4
        for (int e = 0; e < cnt; ++e) {
            int ld = sLd[e];
            if (ld != cur) {
                if (cur >= 0) {
                    accdv[cur * H3 + j] += dva;
                    if (j < H) accdx[cur * H + j] += dxa;
                }
                cur = ld; dva = 0.f; dxa = 0.f;
            }
            float m2 = mst[e * MSTRIDE + H + hh];
            float m3 = mst[e * MSTRIDE + 2 * H + hh];
            float vs = bf2f(vec_bf[(size_t)sSrc[e] * H3 + j]);
            dva += vs * m2 + m3 * sEv[e][c];
            if (j < H) dxa += mst[e * MSTRIDE + j];
        }
        if (cur >= 0) {
            accdv[cur * H3 + j] += dva;
            if (j < H) accdx[cur * H + j] += dxa;
        }
        __syncthreads();
    }
    for (int i = j; i < NPB * H;  i += 384) dx_out[(size_t)n0 * H + i]    = accdx[i];
    for (int i = j; i < NPB * H3; i += 384) dvec_out[(size_t)n0 * H3 + i] = accdv[i];
}

// ---------------- D1a: vec_mid = vec + dvec; x_mid = (x+dx)*c ---------------
__global__ __launch_bounds__(256) void d1a_kernel(const float* __restrict__ x,
        const float* __restrict__ vec, float* __restrict__ B1, float* __restrict__ B2) {
    int i = blockIdx.x * 256 + threadIdx.x;  // over N*H3/4
    float4 dv = ((float4*)B1)[i];
    float4 vv = ((const float4*)vec)[i];
    dv.x += vv.x; dv.y += vv.y; dv.z += vv.z; dv.w += vv.w;
    ((float4*)B1)[i] = dv;
    if (i < NN * H / 4) {
        float4 dx = ((float4*)B2)[i];
        float4 xx = ((const float4*)x)[i];
        dx.x = (xx.x + dx.x) * INV_SQRT_2; dx.y = (xx.y + dx.y) * INV_SQRT_2;
        dx.z = (xx.z + dx.z) * INV_SQRT_2; dx.w = (xx.w + dx.w) * INV_SQRT_2;
        ((float4*)B2)[i] = dx;
    }
}

// ---------------- D1: vproj MFMA + dot/norm fused (48 rows = 16 nodes) ------
__global__ __launch_bounds__(256) void d1_vproj(const float* __restrict__ vec_mid,
        const short* __restrict__ WvT, float* __restrict__ vec1,
        float* __restrict__ vdot, short* __restrict__ vnorm_bf) {
    __shared__ short A_l[48 * AST];
    __shared__ short B_l[128 * AST];
    __shared__ float T1[48 * 132];
    __shared__ float T2[48 * 132];
    int tid = threadIdx.x;
    int w = tid >> 6, l = tid & 63, lm = l & 15, q = l >> 4;
    int r0 = blockIdx.x * 48;
    const float4* ag = (const float4*)(vec_mid + (size_t)r0 * H);
#pragma unroll
    for (int i = 0; i < 6; ++i) {
        int idx = tid + 256 * i;
        float4 a = ag[idx];
        int row = idx >> 5, c4 = idx & 31;
        short4 s4; s4.x = f2bf(a.x); s4.y = f2bf(a.y); s4.z = f2bf(a.z); s4.w = f2bf(a.w);
        *(short4*)&A_l[row * AST + c4 * 4] = s4;
    }
    for (int s = 0; s < 2; ++s) {
        __syncthreads();
        const short8* wg = (const short8*)(WvT + (size_t)s * 128 * 128);
#pragma unroll
        for (int i = 0; i < 8; ++i) {
            int idx = tid + 256 * i;
            int row = idx >> 4, c8 = idx & 15;
            *(short8*)&B_l[row * AST + c8 * 8] = wg[idx];
        }
        __syncthreads();
        short8 bf[2][4];
#pragma unroll
        for (int c = 0; c < 2; ++c)
#pragma unroll
            for (int ks = 0; ks < 4; ++ks)
                bf[c][ks] = *(const short8*)&B_l[((2 * w + c) * 16 + lm) * AST + ks * 32 + q * 8];
        f32x4 acc[3][2];
#pragma unroll
        for (int rt = 0; rt < 3; ++rt) { acc[rt][0] = (f32x4){0.f,0.f,0.f,0.f}; acc[rt][1] = (f32x4){0.f,0.f,0.f,0.f}; }
#pragma unroll
        for (int ks = 0; ks < 4; ++ks)
#pragma unroll
            for (int rt = 0; rt < 3; ++rt) {
                short8 a = *(const short8*)&A_l[(rt * 16 + lm) * AST + ks * 32 + q * 8];
                acc[rt][0] = __builtin_amdgcn_mfma_f32_16x16x32_bf16(a, bf[0][ks], acc[rt][0], 0, 0, 0);
                acc[rt][1] = __builtin_amdgcn_mfma_f32_16x16x32_bf16(a, bf[1][ks], acc[rt][1], 0, 0, 0);
            }
        float* T = s ? T2 : T1;
#pragma unroll
        for (int c = 0; c < 2; ++c) {
            int col = (2 * w + c) * 16 + lm;
#pragma unroll
            for (int rt = 0; rt < 3; ++rt)
#pragma unroll
                for (int r = 0; r < 4; ++r) {
                    int lr = rt * 16 + q * 4 + r;
                    float v = acc[rt][c][r];
                    T[lr * 132 + col] = v;
                    if (s == 0) vec1[(size_t)(r0 + lr) * H + col] = v;
                }
        }
    }
    __syncthreads();
    int nb = blockIdx.x * 16;
#pragma unroll
    for (int i = 0; i < 8; ++i) {
        int p = tid + 256 * i;  // 2048 (node, col) pairs
        int k = p & 127, m = p >> 7;
        float d = 0.f, s2 = 0.f;
#pragma unroll
        for (int c = 0; c < 3; ++c) {
            float v1 = T1[(m * 3 + c) * 132 + k];
            float v2 = T2[(m * 3 + c) * 132 + k];
            d += v1 * v2; s2 += v2 * v2;
        }
        vdot[(size_t)(nb + m) * H + k] = d * INV_SQRT_H;
        vnorm_bf[(size_t)(nb + m) * H + k] = f2bf(sqrtf(s2 + 1e-8f));
    }
}

// ---------------- D2a: u_bf = bf16(ssilu([x_mid, vnorm] @ Wu1 + bu1)) -------
__global__ __launch_bounds__(256) void d2a_mfma(const float* __restrict__ xmid,
        const short* __restrict__ vnorm_bf, const short* __restrict__ Wu1T,
        const float* __restrict__ bu1, short* __restrict__ u_bf) {
    __shared__ short A_l[64 * AST];
    __shared__ short B_l[128 * AST];
    int tid = threadIdx.x;
    int w = tid >> 6, l = tid & 63, lm = l & 15, q = l >> 4;
    int r0 = blockIdx.x * 64;
    f32x4 acc[4][2];
#pragma unroll
    for (int rt = 0; rt < 4; ++rt) { acc[rt][0] = (f32x4){0.f,0.f,0.f,0.f}; acc[rt][1] = (f32x4){0.f,0.f,0.f,0.f}; }
    for (int kh = 0; kh < 2; ++kh) {
        __syncthreads();
        if (kh == 0) {
            const float4* ag = (const float4*)(xmid + (size_t)r0 * H);
#pragma unroll
            for (int i = 0; i < 8; ++i) {
                int idx = tid + 256 * i;
                float4 a = ag[idx];
                int row = idx >> 5, c4 = idx & 31;
                short4 s4; s4.x = f2bf(a.x); s4.y = f2bf(a.y); s4.z = f2bf(a.z); s4.w = f2bf(a.w);
                *(short4*)&A_l[row * AST + c4 * 4] = s4;
            }
        } else {
            const short8* ag = (const short8*)(vnorm_bf + (size_t)r0 * H);
#pragma unroll
            for (int i = 0; i < 4; ++i) {
                int idx = tid + 256 * i;
                int row = idx >> 4, c8 = idx & 15;
                *(short8*)&A_l[row * AST + c8 * 8] = ag[idx];
            }
        }
#pragma unroll
        for (int i = 0; i < 8; ++i) {
            int idx = tid + 256 * i;
            int row = idx >> 4, c8 = idx & 15;
            *(short8*)&B_l[row * AST + c8 * 8] = ((const short8*)Wu1T)[row * 32 + kh * 16 + c8];
        }
        __syncthreads();
        short8 bf[2][4];
#pragma unroll
        for (int c = 0; c < 2; ++c)
#pragma unroll
            for (int ks = 0; ks < 4; ++ks)
                bf[c][ks] = *(const short8*)&B_l[((2 * w + c) * 16 + lm) * AST + ks * 32 + q * 8];
#pragma unroll
        for (int ks = 0; ks < 4; ++ks)
#pragma unroll
            for (int rt = 0; rt < 4; ++rt) {
                short8 a = *(const short8*)&A_l[(rt * 16 + lm) * AST + ks * 32 + q * 8];
                acc[rt][0] = __builtin_amdgcn_mfma_f32_16x16x32_bf16(a, bf[0][ks], acc[rt][0], 0, 0, 0);
                acc[rt][1] = __builtin_amdgcn_mfma_f32_16x16x32_bf16(a, bf[1][ks], acc[rt][1], 0, 0, 0);
            }
    }
#pragma unroll
    for (int c = 0; c < 2; ++c) {
        int col = (2 * w + c) * 16 + lm;
        float bb = bu1[col];
#pragma unroll
        for (int rt = 0; rt < 4; ++rt)
#pragma unroll
            for (int r = 0; r < 4; ++r) {
                int R = r0 + rt * 16 + q * 4 + r;
                u_bf[(size_t)R * H + col] = f2bf(scaled_silu(acc[rt][c][r] + bb));
            }
    }
}

// ---------------- D2b: h = u @ Wu2 + bu2; final outputs ---------------------
__global__ __launch_bounds__(256) void d2b_mfma(const short* __restrict__ u_bf,
        const short* __restrict__ Wu2T, const float* __restrict__ bu2,
        const float* __restrict__ vdot, const float* __restrict__ xmid,
        const float* __restrict__ vec_mid, const float* __restrict__ vec1,
        float* __restrict__ out) {
    __shared__ short A_l[64 * AST];
    __shared__ short B_l[128 * AST];
    int tid = threadIdx.x;
    int w = tid >> 6, l = tid & 63, lm = l & 15, q = l >> 4;
    int r0 = blockIdx.x * 64;
    float* out_vec = out;
    float* out_x = out + (size_t)NN * H3;
    const short8* ag = (const short8*)(u_bf + (size_t)r0 * H);
#pragma unroll
    for (int i = 0; i < 4; ++i) {
        int idx = tid + 256 * i;
        int row = idx >> 4, c8 = idx & 15;
        *(short8*)&A_l[row * AST + c8 * 8] = ag[idx];
    }
    // stage slice 0, keep frags; stage slice 1, keep frags; dual K-loop
    short8 bf0[2][4], bf1[2][4];
    __syncthreads();
    {
        const short8* wg = (const short8*)Wu2T;
#pragma unroll
        for (int i = 0; i < 8; ++i) {
            int idx = tid + 256 * i;
            int row = idx >> 4, c8 = idx & 15;
            *(short8*)&B_l[row * AST + c8 * 8] = wg[idx];
        }
    }
    __syncthreads();
#pragma unroll
    for (int c = 0; c < 2; ++c)
#pragma unroll
        for (int ks = 0; ks < 4; ++ks)
            bf0[c][ks] = *(const short8*)&B_l[((2 * w + c) * 16 + lm) * AST + ks * 32 + q * 8];
    __syncthreads();
    {
        const short8* wg = (const short8*)(Wu2T + 128 * 128);
#pragma unroll
        for (int i = 0; i < 8; ++i) {
            int idx = tid + 256 * i;
            int row = idx >> 4, c8 = idx & 15;
            *(short8*)&B_l[row * AST + c8 * 8] = wg[idx];
        }
    }
    __syncthreads();
#pragma unroll
    for (int c = 0; c < 2; ++c)
#pragma unroll
        for (int ks = 0; ks < 4; ++ks)
            bf1[c][ks] = *(const short8*)&B_l[((2 * w + c) * 16 + lm) * AST + ks * 32 + q * 8];
    f32x4 acc0[4][2], acc1[4][2];
#pragma unroll
    for (int rt = 0; rt < 4; ++rt) {
        acc0[rt][0] = (f32x4){0.f,0.f,0.f,0.f}; acc0[rt][1] = (f32x4){0.f,0.f,0.f,0.f};
        acc1[rt][0] = (f32x4){0.f,0.f,0.f,0.f}; acc1[rt][1] = (f32x4){0.f,0.f,0.f,0.f};
    }
#pragma unroll
    for (int ks = 0; ks < 4; ++ks)
#pragma unroll
        for (int rt = 0; rt < 4; ++rt) {
            short8 a = *(const short8*)&A_l[(rt * 16 + lm) * AST + ks * 32 + q * 8];
            acc0[rt][0] = __builtin_amdgcn_mfma_f32_16x16x32_bf16(a, bf0[0][ks], acc0[rt][0], 0, 0, 0);
            acc0[rt][1] = __builtin_amdgcn_mfma_f32_16x16x32_bf16(a, bf0[1][ks], acc0[rt][1], 0, 0, 0);
            acc1[rt][0] = __builtin_amdgcn_mfma_f32_16x16x32_bf16(a, bf1[0][ks], acc1[rt][0], 0, 0, 0);
            acc1[rt][1] = __builtin_amdgcn_mfma_f32_16x16x32_bf16(a, bf1[1][ks], acc1[rt][1], 0, 0, 0);
        }
    // epilogue: out_x = x_mid + (xv1 + xv2*vdot)*INV_SQRT_2
#pragma unroll
    for (int c = 0; c < 2; ++c) {
        int col = (2 * w + c) * 16 + lm;
        float bb0 = bu2[col], bb1 = bu2[H + col];
#pragma unroll
        for (int rt = 0; rt < 4; ++rt)
#pragma unroll
            for (int r = 0; r < 4; ++r) {
                int R = r0 + rt * 16 + q * 4 + r;
                float xv1 = acc0[rt][c][r] + bb0;
                float xv2 = acc1[rt][c][r] + bb1;
                float dx2 = (xv1 + xv2 * vdot[(size_t)R * H + col]) * INV_SQRT_2;
                out_x[(size_t)R * H + col] = xmid[(size_t)R * H + col] + dx2;
            }
    }
    // slice 2 (xv3) -> out_vec
    __syncthreads();
    {
        const short8* wg = (const short8*)(Wu2T + 2 * 128 * 128);
#pragma unroll
        for (int i = 0; i < 8; ++i) {
            int idx = tid + 256 * i;
            int row = idx >> 4, c8 = idx & 15;
            *(short8*)&B_l[row * AST + c8 * 8] = wg[idx];
        }
    }
    __syncthreads();
#pragma unroll
    for (int c = 0; c < 2; ++c)
#pragma unroll
        for (int ks = 0; ks < 4; ++ks)
            bf0[c][ks] = *(const short8*)&B_l[((2 * w + c) * 16 + lm) * AST + ks * 32 + q * 8];
#pragma unroll
    for (int rt = 0; rt < 4; ++rt) { acc0[rt][0] = (f32x4){0.f,0.f,0.f,0.f}; acc0[rt][1] = (f32x4){0.f,0.f,0.f,0.f}; }
#pragma unroll
    for (int ks = 0; ks < 4; ++ks)
#pragma unroll
        for (int rt = 0; rt < 4; ++rt) {
            short8 a = *(const short8*)&A_l[(rt * 16 + lm) * AST + ks * 32 + q * 8];
            acc0[rt][0] = __builtin_amdgcn_mfma_f32_16x16x32_bf16(a, bf0[0][ks], acc0[rt][0], 0, 0, 0);
            acc0[rt][1] = __builtin_amdgcn_mfma_f32_16x16x32_bf16(a, bf0[1][ks], acc0[rt][1], 0, 0, 0);
        }
#pragma unroll
    for (int c = 0; c < 2; ++c) {
        int col = (2 * w + c) * 16 + lm;
        float bb2 = bu2[2 * H + col];
#pragma unroll
        for (int rt = 0; rt < 4; ++rt)
#pragma unroll
            for (int r = 0; r < 4; ++r) {
                int R = r0 + rt * 16 + q * 4 + r;
                float xv3 = acc0[rt][c][r] + bb2;
#pragma unroll
                for (int c3 = 0; c3 < 3; ++c3) {
                    size_t idx = (size_t)R * H3 + c3 * H + col;
                    out_vec[idx] = vec_mid[idx] + xv3 * vec1[idx];
                }
            }
    }
}

extern "C" void kernel_launch(void* const* d_in, const int* in_sizes, int n_in,
                              void* d_out, int out_size, void* d_ws, size_t ws_size,
                              hipStream_t stream) {
    const float* x    = (const float*)d_in[0];
    const float* vec  = (const float*)d_in[1];
    const int*   eidx = (const int*)d_in[2];
    const float* eemb = (const float*)d_in[3];
    const float* evec = (const float*)d_in[4];
    const float* lng  = (const float*)d_in[5];
    const float* lnb  = (const float*)d_in[6];
    const float* W1   = (const float*)d_in[7];
    const float* b1   = (const float*)d_in[8];
    const float* W2   = (const float*)d_in[9];
    const float* b2   = (const float*)d_in[10];
    const float* Wr   = (const float*)d_in[11];
    const float* br   = (const float*)d_in[12];
    const float* Wv   = (const float*)d_in[13];
    const float* Wu1  = (const float*)d_in[14];
    const float* bu1  = (const float*)d_in[15];
    const float* Wu2  = (const float*)d_in[16];
    const float* bu2  = (const float*)d_in[17];

    // workspace layout:
    // B0: N*384 f32 : xh_bf16 (as shorts) -> vec1 f32
    // B1: N*384 f32 : dvec -> vec_mid
    // B2: N*128 f32 : t(LN) -> dx -> x_mid
    // B3: N*128 f32 : h1_bf16 (as shorts) -> vec_dot f32
    // B4: N*128 f32 : [sort scratch + WrT16] -> vnorm_bf16 + u_bf16
    // B5: vec_bf16 (N*384 shorts) + bf16 transposed weights
    float* B0 = (float*)d_ws;
    float* B1 = B0 + (size_t)NN * H3;
    float* B2 = B1 + (size_t)NN * H3;
    float* B3 = B2 + (size_t)NN * H;
    float* B4 = B3 + (size_t)NN * H;
    short* B5 = (short*)(B4 + (size_t)NN * H);
    float* out = (float*)d_out;

    int* row_ptr = (int*)B4;
    int* cursor  = row_ptr + 32772;
    int* perm    = cursor + 32768;
    int* srcs_s  = perm + NE;
    int* dsts_s  = srcs_s + NE;
    float* ev_s  = (float*)(dsts_s + NE);
    short* WrT16 = (short*)(ev_s + (size_t)NE * 3);

    short* vec_bf = B5;
    short* W1T  = vec_bf + (size_t)NN * H3;
    short* W2T  = W1T + 128 * 128;
    short* WvT  = W2T + 128 * 384;
    short* Wu1T = WvT + 128 * 256;
    short* Wu2T = Wu1T + 256 * 128;

    short* xh_bf    = (short*)B0;
    short* h1_bf    = (short*)B3;
    short* vnorm_bf = (short*)B4;
    short* u_bf     = vnorm_bf + (size_t)NN * H;

    // weight conversions + vec bf16 copy
    cvtT_kernel<<<64,  256, 0, stream>>>(W1,  W1T,  128, 128);
    cvtT_kernel<<<192, 256, 0, stream>>>(W2,  W2T,  128, 384);
    cvtT_kernel<<<128, 256, 0, stream>>>(Wv,  WvT,  128, 256);
    cvtT_kernel<<<128, 256, 0, stream>>>(Wu1, Wu1T, 256, 128);
    cvtT_kernel<<<192, 256, 0, stream>>>(Wu2, Wu2T, 128, 384);
    wrt_kernel<<<(H3 * RB) / 256, 256, 0, stream>>>(Wr, WrT16);
    veccvt_kernel<<<(NN * H3 / 4) / 256, 256, 0, stream>>>(vec, vec_bf);

    // node message path
    ln_kernel<<<NN / 4, 256, 0, stream>>>(x, lng, lnb, B2);
    g1_mfma<<<NN / 64, 256, 0, stream>>>(B2, W1T, b1, h1_bf);
    g2_mfma<<<NN / 64, 256, 0, stream>>>(h1_bf, W2T, b2, xh_bf);

    // dst counting sort -> CSR
    hipMemsetAsync(row_ptr, 0, 32768 * sizeof(int), stream);
    hist_kernel<<<NE / 256, 256, 0, stream>>>(eidx, row_ptr);
    scan_kernel<<<1, 1024, 0, stream>>>(row_ptr, row_ptr, cursor);
    scatter_kernel<<<NE / 256, 256, 0, stream>>>(eidx, evec, cursor, perm, srcs_s, dsts_s, ev_s);

    // fused edge message + segment reduce (dx -> B2, dvec -> B1)
    edge_mfma_kernel<<<NN / NPB, 384, 0, stream>>>(row_ptr, perm, srcs_s, dsts_s, ev_s,
                                                   eemb, WrT16, br, xh_bf, vec_bf, B2, B1);

    // update path
    d1a_kernel<<<(NN * H3 / 4) / 256, 256, 0, stream>>>(x, vec, B1, B2);
    d1_vproj<<<(NN * 3) / 48, 256, 0, stream>>>(B1, WvT, B0, B3, vnorm_bf);
    d2a_mfma<<<NN / 64, 256, 0, stream>>>(B2, vnorm_bf, Wu1T, bu1, u_bf);
    d2b_mfma<<<NN / 64, 256, 0, stream>>>(u_bf, Wu2T, bu2, B3, B2, B1, B0, out);
}